// Round 17
// baseline (167.370 us; speedup 1.0000x reference)
//
#include <hip/hip_runtime.h>

typedef __bf16 bf16;
typedef __attribute__((ext_vector_type(8))) __bf16 bf16x8;
typedef __attribute__((ext_vector_type(4))) float f32x4;

#define MPTS 40960
#define NC 15
#define GX 1280
#define GY 948
#define HH 640
#define WW 474
#define CROPN 320

#define K1 960    // A1 row width (ky padded 948->960)
#define K1F 480   // folded ky K for GEMM1
#define M1 384    // rows: [0,192)=cos n, [192,384)=sin n
#define K2F 672   // folded kx
#define M2F 320

#define NTX 80
#define NTY 30
#define NTILE (NTX*NTY)   // 2400
#define MAXENT (MPTS*4)
#define GLDT 40   // gather LDS row stride (bf16): 80B, 16B-aligned, 2-way banks

// ---------- modified Bessel I0 ----------
__device__ __forceinline__ float i0f_dev(float x){
  if (x < 3.75f){
    float t = x*(1.0f/3.75f); t *= t;
    return 1.0f + t*(3.5156229f + t*(3.0899424f + t*(1.2067492f +
                 t*(0.2659732f + t*(0.0360768f + t*0.0045813f)))));
  } else {
    float t = 3.75f/x;
    float p = 0.39894228f + t*(0.01328592f + t*(0.00225319f + t*(-0.00157565f +
              t*(0.00916281f + t*(-0.02057706f + t*(0.02635537f +
              t*(-0.01647633f + t*0.00392377f)))))));
    return __expf(x)*rsqrtf(x)*p;
  }
}

__device__ __forceinline__ float kb_w(float u){
  float a = 1.0f - u*u*(1.0f/9.0f);
  return i0f_dev(14.04f*sqrtf(fmaxf(a, 0.0f)))*(1.0f/6.0f);
}

#define B1_ELEMS (M1*K1F)
#define W2_ELEMS (M2F*K2F)
#define PREP_BLOCKS ((MPTS+255)/256)
#define GEN_BLOCKS  ((B1_ELEMS+W2_ELEMS+255)/256)

// ---------- fused prep (ydc/wtab/itab/hist) + twiddle gen ----------
__global__ void prep_gen(const float* __restrict__ kr, const float* __restrict__ ki,
                         const float* __restrict__ dc, const float* __restrict__ ktraj,
                         float* __restrict__ ydc, float* __restrict__ wtab,
                         int2* __restrict__ itab, int* __restrict__ bhist,
                         bf16* __restrict__ B1, bf16* __restrict__ W2c,
                         bf16* __restrict__ W2s){
  int b = blockIdx.x;
  if (b < PREP_BLOCKS){
    int m = b*256 + threadIdx.x;
    if (m >= MPTS) return;
    float d = dc[m];
    #pragma unroll
    for (int c=0;c<NC;++c){
      ydc[((size_t)m*NC + c)*2    ] = kr[(size_t)c*MPTS + m]*d;
      ydc[((size_t)m*NC + c)*2 + 1] = ki[(size_t)c*MPTS + m]*d;
    }
    const float PI2 = 6.28318530717958647692f;
    float tmx = ktraj[m]        * ((float)GX/PI2);
    float tmy = ktraj[MPTS + m] * ((float)GY/PI2);
    float bx = floorf(tmx - 3.0f), by = floorf(tmy - 3.0f);
    float wx[6], wy[6];
    #pragma unroll
    for (int j=0;j<6;++j){
      wx[j] = kb_w(tmx - (bx + (float)(j+1)));
      wy[j] = kb_w(tmy - (by + (float)(j+1)));
    }
    float4* wt = (float4*)(wtab + (size_t)m*12);
    wt[0] = make_float4(wx[0], wx[1], wx[2], wx[3]);
    wt[1] = make_float4(wx[4], wx[5], wy[0], wy[1]);
    wt[2] = make_float4(wy[2], wy[3], wy[4], wy[5]);
    int ix0 = ((int)bx + 1) % GX; if (ix0 < 0) ix0 += GX;
    int iy0 = ((int)by + 1) % GY; if (iy0 < 0) iy0 += GY;
    itab[m] = make_int2(ix0, iy0);
    int tx0 = ix0 >> 4, tx1 = ((ix0 + 5) % GX) >> 4;
    int ty0 = iy0 >> 5, ty1 = ((iy0 + 5) % GY) >> 5;
    atomicAdd(&bhist[tx0*NTY+ty0],1);
    if (tx1!=tx0) atomicAdd(&bhist[tx1*NTY+ty0],1);
    if (ty1!=ty0){
      atomicAdd(&bhist[tx0*NTY+ty1],1);
      if (tx1!=tx0) atomicAdd(&bhist[tx1*NTY+ty1],1);
    }
    return;
  }
  int i = (b - PREP_BLOCKS)*256 + threadIdx.x;
  if (i < B1_ELEMS){
    int r = i / K1F, k = i - r*K1F;
    float v = 0.f;
    if (k <= 474){
      if (r < 192){
        int n = r;
        if (n <= 160){
          int rem = (k * n) % GY;
          float ang = 6.28318530717958647692f * (float)rem / (float)GY;
          float s, c; sincosf(ang, &s, &c); v = c;
        }
      } else {
        int n = r - 192;
        if (n >= 1 && n <= 160){
          int rem = (k * n) % GY;
          float ang = 6.28318530717958647692f * (float)rem / (float)GY;
          float s, c; sincosf(ang, &s, &c); v = s;
        }
      }
    }
    B1[i] = (bf16)v;
  } else if (i < B1_ELEMS + W2_ELEMS){
    int j = i - B1_ELEMS;
    int r = j / K2F, k = j - r*K2F;
    int nx = (r < 160) ? (1120 + r) : (r - 160);
    float vc = 0.f, vs = 0.f;
    if (k < 640){
      int rem = (k * nx) % GX;
      float ang = 6.28318530717958647692f * (float)rem / (float)GX;
      float s, c; sincosf(ang, &s, &c);
      vc = c; vs = s;
    } else if (k == 640){
      vc = (nx & 1) ? -1.f : 1.f; vs = 0.f;
    }
    W2c[j] = (bf16)vc;
    W2s[j] = (bf16)vs;
  }
}

#define SCAN_PER 10
__global__ __launch_bounds__(256) void bin_scan(const int* __restrict__ bhist,
                                                int* __restrict__ bstart,
                                                int* __restrict__ bcur){
  __shared__ int ps[256];
  int t = threadIdx.x;
  int v[SCAN_PER]; int s = 0;
  #pragma unroll
  for (int j=0;j<SCAN_PER;++j){ int i = t*SCAN_PER+j; v[j] = (i<NTILE)?bhist[i]:0; s += v[j]; }
  ps[t] = s; __syncthreads();
  for (int off=1; off<256; off<<=1){
    int x = (t>=off) ? ps[t-off] : 0;
    __syncthreads();
    ps[t] += x;
    __syncthreads();
  }
  int run = (t==0) ? 0 : ps[t-1];
  #pragma unroll
  for (int j=0;j<SCAN_PER;++j){
    int i = t*SCAN_PER+j;
    if (i<NTILE){ bstart[i]=run; bcur[i]=run; }
    run += v[j];
  }
}

__global__ void bin_fill(const int2* __restrict__ itab, int* __restrict__ bcur,
                         int* __restrict__ bent){
  int m = blockIdx.x*256 + threadIdx.x;
  if (m >= MPTS) return;
  int2 ii = itab[m];
  int tx0 = ii.x >> 4, tx1 = ((ii.x + 5) % GX) >> 4;
  int ty0 = ii.y >> 5, ty1 = ((ii.y + 5) % GY) >> 5;
  int p = atomicAdd(&bcur[tx0*NTY+ty0],1); bent[p] = m;
  if (tx1!=tx0){ p = atomicAdd(&bcur[tx1*NTY+ty0],1); bent[p] = m; }
  if (ty1!=ty0){
    p = atomicAdd(&bcur[tx0*NTY+ty1],1); bent[p] = m;
    if (tx1!=tx0){ p = atomicAdd(&bcur[tx1*NTY+ty1],1); bent[p] = m; }
  }
}

// ---------- MFMA tile gather: 16x32 tile, 512 threads ----------
// Phase A: thread t owns cell t; computes bf16 weight per sample slot -> Wm[512][32]
// Phase B: C[cell][coilcomp] += Wm x Yt via mfma_f32_16x16x32_bf16 (K=32 slab)
template<int BC>
__global__ __launch_bounds__(512, 3) void tile_gather_mfma(const float* __restrict__ ydc,
                                                           const float* __restrict__ wtab,
                                                           const int2* __restrict__ itab,
                                                           const int* __restrict__ bstart,
                                                           const int* __restrict__ bend,
                                                           const int* __restrict__ bent,
                                                           bf16* __restrict__ A1, int c0){
  constexpr int NF = (2*BC + 15)/16;   // N fragments of 16 coil-components
  int tile = blockIdx.x;
  int tx = tile / NTY, ty = tile - tx*NTY;
  int x0 = tx*16, y0 = ty*32;
  int t = threadIdx.x;
  int lane = t & 63, wave = t >> 6;    // 8 waves
  int kxl = t >> 5, kyl = t & 31;      // owned cell
  int kxi = x0 + kxl, kyi = y0 + kyl;

  __shared__ float swx[32][6], swy[32][6];
  __shared__ int   six0[32], siy0[32];
  __shared__ bf16  Wm[512*GLDT];       // [cell][slot], stride 40
  __shared__ bf16  Yt[32*GLDT];        // [coilcomp][slot], stride 40

  f32x4 zero = {0.f,0.f,0.f,0.f};
  f32x4 acc[4][NF];
  #pragma unroll
  for (int m=0;m<4;++m)
    #pragma unroll
    for (int n=0;n<NF;++n) acc[m][n] = zero;

  int lr = lane & 15, lk = (lane >> 4) * 8;
  int beg = bstart[tile], end = bend[tile];

  for (int s0 = beg; s0 < end; s0 += 32){
    int ns = end - s0; if (ns > 32) ns = 32;
    __syncthreads();
    // stage sample meta (threads 0..ns-1)
    if (t < ns){
      int m = bent[s0+t];
      const float4* wt = (const float4*)(wtab + (size_t)m*12);
      float4 w0 = wt[0], w1 = wt[1], w2 = wt[2];
      swx[t][0]=w0.x; swx[t][1]=w0.y; swx[t][2]=w0.z; swx[t][3]=w0.w;
      swx[t][4]=w1.x; swx[t][5]=w1.y;
      swy[t][0]=w1.z; swy[t][1]=w1.w; swy[t][2]=w2.x; swy[t][3]=w2.y;
      swy[t][4]=w2.z; swy[t][5]=w2.w;
      int2 ii = itab[m];
      six0[t] = ii.x; siy0[t] = ii.y;
    }
    // stage Yt[c2][s] (zero-padded)
    for (int i = t; i < NF*16*32; i += 512){
      int c2 = i >> 5, s = i & 31;
      float v = 0.f;
      if (s < ns && c2 < 2*BC){
        int m = bent[s0+s];
        v = ydc[((size_t)m*NC + c0)*2 + c2];
      }
      Yt[c2*GLDT + s] = (bf16)v;
    }
    __syncthreads();
    // phase A: weights for own cell
    for (int s = 0; s < ns; ++s){
      int lx = kxi - six0[s]; if (lx < 0) lx += GX;
      int ly = kyi - siy0[s]; if (ly < 0) ly += GY;
      float w = (lx < 6 && ly < 6) ? swx[s][lx] * swy[s][ly] : 0.0f;
      Wm[t*GLDT + s] = (bf16)w;
    }
    for (int s = ns; s < 32; ++s) Wm[t*GLDT + s] = (bf16)0.f;
    __syncthreads();
    // phase B: MFMA — wave handles M-fragments [wave*4, wave*4+4)
    bf16x8 bg[NF];
    #pragma unroll
    for (int n=0;n<NF;++n)
      bg[n] = *(const bf16x8*)(Yt + (n*16 + lr)*GLDT + lk);
    #pragma unroll
    for (int m=0;m<4;++m){
      bf16x8 af = *(const bf16x8*)(Wm + ((wave*4 + m)*16 + lr)*GLDT + lk);
      #pragma unroll
      for (int n=0;n<NF;++n)
        acc[m][n] = __builtin_amdgcn_mfma_f32_16x16x32_bf16(af, bg[n], acc[m][n], 0, 0, 0);
    }
  }

  // epilogue: C[cell][c2] -> A1 rows
  int rowb = (lane >> 4) * 4;
  #pragma unroll
  for (int m=0;m<4;++m){
    #pragma unroll
    for (int n=0;n<NF;++n){
      int c2 = n*16 + lr;
      if (c2 < 2*BC){
        int c = c2 >> 1, ri = c2 & 1;
        #pragma unroll
        for (int r=0;r<4;++r){
          int cell = (wave*4 + m)*16 + rowb + r;
          int cx = cell >> 5, cy = cell & 31;
          int kx = x0 + cx, ky = y0 + cy;
          float v = (ky < GY) ? acc[m][n][r] : 0.0f;
          A1[((size_t)((c*GX + kx)*2 + ri))*K1 + ky] = (bf16)v;
        }
      }
    }
  }
}

// ---------- GEMM1 with in-staging ky-fold, 512 threads / 8 waves (R16 known-good) ----------
#define BM 128
#define BN 128
#define BK 32
#define LDT 40

__device__ __forceinline__ void fold8(bf16x8 own, bf16x8 mA, bf16x8 mB, int k0,
                                      bf16x8& pv, bf16x8& mv){
  float mir[8];
  mir[0]=(float)mB[4]; mir[1]=(float)mB[3]; mir[2]=(float)mB[2]; mir[3]=(float)mB[1];
  mir[4]=(float)mB[0]; mir[5]=(float)mA[7]; mir[6]=(float)mA[6]; mir[7]=(float)mA[5];
  #pragma unroll
  for (int j=0;j<8;++j){
    float mm = (k0 + j == 474) ? 0.f : mir[j];
    float ov = (float)own[j];
    pv[j] = (bf16)(ov + mm);
    mv[j] = (bf16)(ov - mm);
  }
}

__global__ __launch_bounds__(512) void gemm1_fold(const bf16* __restrict__ A,
                                                  const bf16* __restrict__ B,
                                                  bf16* __restrict__ C,
                                                  int ldc){
  int total = gridDim.x;
  int qq = total >> 3, rr = total & 7;
  int d = blockIdx.x;
  int xcd = d & 7, jj = d >> 3;
  int L = (xcd < rr) ? (xcd*(qq+1) + jj) : (rr*(qq+1) + (xcd-rr)*qq + jj);
  size_t tileM = (size_t)(L % 3) * BM;
  size_t tileN = (size_t)(L / 3) * BN;

  __shared__ bf16 As[BM*LDT];
  __shared__ bf16 Bp[BM*LDT];
  __shared__ bf16 Bm[BM*LDT];
  int t = threadIdx.x;
  int lane = t & 63;
  int wave = t >> 6;
  int wm = wave >> 2, wn = wave & 3;
  bool isCos = (tileM + (size_t)wm*64) < 192;

  f32x4 zero = {0.f, 0.f, 0.f, 0.f};
  f32x4 acc[4][2];
  #pragma unroll
  for (int m=0;m<4;++m)
    #pragma unroll
    for (int n=0;n<2;++n) acc[m][n] = zero;

  int r0 = t >> 2;
  int kc = (t & 3) * 8;
  const bf16* Arow = A + (tileM + r0) * (size_t)K1F + kc;
  const bf16* Brow = B + (tileN + r0) * (size_t)K1;

  bf16x8 a0  = *(const bf16x8*)(Arow);
  bf16x8 o0  = *(const bf16x8*)(Brow + kc);
  bf16x8 mA0 = *(const bf16x8*)(Brow + 936 - kc);
  bf16x8 mB0 = *(const bf16x8*)(Brow + 944 - kc);

  int lr = lane & 15, lk = (lane >> 4) * 8;

  for (int kt = 0; kt < K1F; kt += BK){
    bf16x8 p0, m0;
    fold8(o0, mA0, mB0, kt + kc, p0, m0);
    __syncthreads();
    *(bf16x8*)(As + r0*LDT + kc) = a0;
    *(bf16x8*)(Bp + r0*LDT + kc) = p0;
    *(bf16x8*)(Bm + r0*LDT + kc) = m0;
    __syncthreads();

    if (kt + BK < K1F){
      int kn = kt + BK + kc;
      a0  = *(const bf16x8*)(Arow + kt + BK);
      o0  = *(const bf16x8*)(Brow + kn);
      mA0 = *(const bf16x8*)(Brow + 936 - kn);
      mB0 = *(const bf16x8*)(Brow + 944 - kn);
    }

    const bf16* Bsel = isCos ? Bp : Bm;
    bf16x8 af[4], bg[2];
    #pragma unroll
    for (int m=0;m<4;++m)
      af[m] = *(const bf16x8*)(As + (wm*64 + m*16 + lr)*LDT + lk);
    #pragma unroll
    for (int n=0;n<2;++n)
      bg[n] = *(const bf16x8*)(Bsel + (wn*32 + n*16 + lr)*LDT + lk);
    #pragma unroll
    for (int m=0;m<4;++m)
      #pragma unroll
      for (int n=0;n<2;++n)
        acc[m][n] = __builtin_amdgcn_mfma_f32_16x16x32_bf16(af[m], bg[n], acc[m][n], 0, 0, 0);
  }

  int lrow = (lane >> 4) * 4;
  #pragma unroll
  for (int m=0;m<4;++m)
    #pragma unroll
    for (int n=0;n<2;++n){
      size_t row = tileM + wm*64 + m*16 + lrow;
      size_t col = tileN + wn*32 + n*16 + lr;
      #pragma unroll
      for (int r2=0;r2<4;++r2)
        C[(row + r2)*(size_t)ldc + col] = (bf16)acc[m][n][r2];
    }
}

// ---------- pack C1t(bf16) -> folded A2p/A2m (cos row n; sin row 192+n) ----------
__global__ void pack_fold(const bf16* __restrict__ C1t, bf16* __restrict__ A2p,
                          bf16* __restrict__ A2m, int nb, int ldc1){
  int i = blockIdx.x*256 + threadIdx.x;
  if (i >= nb*161*80) return;
  int kxg = i % 80;
  int rem = i / 80;
  int n   = rem % 161;
  int cl  = rem / 161;
  int kx0 = kxg*8;

  const bf16* rowC = C1t + (size_t)n*ldc1;
  const bf16* rowS = C1t + (size_t)(192+n)*ldc1;
  int ob = cl*2560 + kx0*2;
  int mb = 1280 - kx0 - 8;
  int mbb = cl*2560 + mb*2;

  float CRo[8], CIo[8], SRo[8], SIo[8];
  {
    bf16x8 c0 = *(const bf16x8*)(rowC + ob);
    bf16x8 c1 = *(const bf16x8*)(rowC + ob + 8);
    bf16x8 s0 = *(const bf16x8*)(rowS + ob);
    bf16x8 s1 = *(const bf16x8*)(rowS + ob + 8);
    #pragma unroll
    for (int j=0;j<4;++j){
      CRo[j]   = (float)c0[2*j]; CIo[j]   = (float)c0[2*j+1];
      CRo[j+4] = (float)c1[2*j]; CIo[j+4] = (float)c1[2*j+1];
      SRo[j]   = (float)s0[2*j]; SIo[j]   = (float)s0[2*j+1];
      SRo[j+4] = (float)s1[2*j]; SIo[j+4] = (float)s1[2*j+1];
    }
  }
  float CRm[16], CIm[16], SRm[16], SIm[16];
  {
    #pragma unroll
    for (int h=0;h<4;++h){
      bf16x8 cm = *(const bf16x8*)(rowC + mbb + 8*h);
      bf16x8 sm = *(const bf16x8*)(rowS + mbb + 8*h);
      #pragma unroll
      for (int j=0;j<4;++j){
        CRm[h*4+j] = (float)cm[2*j]; CIm[h*4+j] = (float)cm[2*j+1];
        SRm[h*4+j] = (float)sm[2*j]; SIm[h*4+j] = (float)sm[2*j+1];
      }
    }
  }

  #pragma unroll
  for (int br=0; br<2; ++br){
    bool valid = (br==0) ? (n <= 159) : (n >= 1);
    if (!valid) continue;
    int qv = (br==0) ? (160+n) : (160-n);
    bf16x8 pre, mre, pim, mim;
    #pragma unroll
    for (int j=0;j<8;++j){
      float tro, tio, trm, tim_;
      if (br==0){ tro = CRo[j]-SIo[j]; tio = SRo[j]+CIo[j]; }
      else      { tro = CRo[j]+SIo[j]; tio = CIo[j]-SRo[j]; }
      int mi = 8 - j;
      if (br==0){ trm = CRm[mi]-SIm[mi]; tim_ = SRm[mi]+CIm[mi]; }
      else      { trm = CRm[mi]+SIm[mi]; tim_ = CIm[mi]-SRm[mi]; }
      if (j==0 && kxg==0){ trm = 0.f; tim_ = 0.f; }
      pre[j] = (bf16)(tro + trm); mre[j] = (bf16)(tro - trm);
      pim[j] = (bf16)(tio + tim_); mim[j] = (bf16)(tio - tim_);
    }
    size_t r0 = ((size_t)(cl*640 + 2*qv))*K2F;
    *(bf16x8*)(A2p + r0 + kx0)        = pre;
    *(bf16x8*)(A2m + r0 + kx0)        = mre;
    *(bf16x8*)(A2p + r0 + K2F + kx0)  = pim;
    *(bf16x8*)(A2m + r0 + K2F + kx0)  = mim;
    if (kxg == 0){
      bf16x8 c6 = *(const bf16x8*)(rowC + cl*2560 + 1280);
      bf16x8 s6 = *(const bf16x8*)(rowS + cl*2560 + 1280);
      float CR6 = (float)c6[0], CI6 = (float)c6[1];
      float SR6 = (float)s6[0], SI6 = (float)s6[1];
      float t6re, t6im;
      if (br==0){ t6re = CR6-SI6; t6im = SR6+CI6; }
      else      { t6re = CR6+SI6; t6im = CI6-SR6; }
      A2p[r0 + 640]       = (bf16)t6re;
      A2p[r0 + K2F + 640] = (bf16)t6im;
      A2m[r0 + 640]       = (bf16)0.f;
      A2m[r0 + K2F + 640] = (bf16)0.f;
    }
  }
}

// ---------- bf16 GEMM, 64x64 tile, fp32 C, both folds in one launch ----------
__global__ __launch_bounds__(256) void gemm_bt64_2(const bf16* __restrict__ Acos,
                                                   const bf16* __restrict__ Bcos,
                                                   float* __restrict__ Ccos,
                                                   const bf16* __restrict__ Asin,
                                                   const bf16* __restrict__ Bsin,
                                                   float* __restrict__ Csin,
                                                   int K, int ldc){
  const bf16* A = blockIdx.z ? Asin : Acos;
  const bf16* B = blockIdx.z ? Bsin : Bcos;
  float*      C = blockIdx.z ? Csin : Ccos;

  __shared__ bf16 As[64*LDT];
  __shared__ bf16 Bs[64*LDT];
  int t = threadIdx.x;
  int lane = t & 63;
  int wave = t >> 6;
  int wm = wave >> 1, wn = wave & 1;
  size_t tileM = (size_t)blockIdx.x * 64;
  size_t tileN = (size_t)blockIdx.y * 64;

  const bf16* Ab = A + tileM * K;
  const bf16* Bb = B + tileN * K;

  f32x4 zero = {0.f, 0.f, 0.f, 0.f};
  f32x4 acc[2][2];
  #pragma unroll
  for (int m=0;m<2;++m)
    #pragma unroll
    for (int n=0;n<2;++n) acc[m][n] = zero;

  int r0 = t >> 2;
  int kc = (t & 3) * 8;
  size_t aoff = (size_t)r0 * K + kc;

  bf16x8 a0 = *(const bf16x8*)(Ab + aoff);
  bf16x8 b0 = *(const bf16x8*)(Bb + aoff);

  int lr = lane & 15, lk = (lane >> 4) * 8;

  for (int kt = 0; kt < K; kt += BK){
    __syncthreads();
    *(bf16x8*)(As + r0*LDT + kc) = a0;
    *(bf16x8*)(Bs + r0*LDT + kc) = b0;
    __syncthreads();

    bool more = (kt + BK) < K;
    if (more){
      size_t o = aoff + kt + BK;
      a0 = *(const bf16x8*)(Ab + o);
      b0 = *(const bf16x8*)(Bb + o);
    }

    bf16x8 af[2], bg[2];
    #pragma unroll
    for (int m=0;m<2;++m)
      af[m] = *(const bf16x8*)(As + (wm*32 + m*16 + lr)*LDT + lk);
    #pragma unroll
    for (int n=0;n<2;++n)
      bg[n] = *(const bf16x8*)(Bs + (wn*32 + n*16 + lr)*LDT + lk);
    #pragma unroll
    for (int m=0;m<2;++m)
      #pragma unroll
      for (int n=0;n<2;++n)
        acc[m][n] = __builtin_amdgcn_mfma_f32_16x16x32_bf16(af[m], bg[n], acc[m][n], 0, 0, 0);
  }

  int lrow = (lane >> 4) * 4;
  #pragma unroll
  for (int m=0;m<2;++m)
    #pragma unroll
    for (int n=0;n<2;++n){
      size_t row = tileM + wm*32 + m*16 + lrow;
      size_t col = tileN + wn*32 + n*16 + lr;
      #pragma unroll
      for (int r=0;r<4;++r)
        C[(row + r)*(size_t)ldc + col] = acc[m][n][r];
    }
}

// ---------- deapodization ----------
__device__ __forceinline__ float deapod_f(float n, float G){
  float x = 3.14159265358979323846f * 6.0f * n / G;
  float z = 197.1216f - x*x;
  float sz = sqrtf(fabsf(z) + 1e-12f);
  float K;
  if (z > 0.0f){
    float e = __expf(sz);
    K = (e - 1.0f/e)*0.5f/sz;
  } else {
    K = __sinf(sz)/sz;
  }
  return 1.0f/K;
}

// ---------- fused coil combine + deapod + magnitude (single-batch path) ----------
__global__ void combine_final(const float* __restrict__ Oc, const float* __restrict__ Os,
                              const float* __restrict__ smr, const float* __restrict__ smi,
                              float* __restrict__ out, int bc, int ldo){
  int i = blockIdx.x*256 + threadIdx.x;
  if (i >= CROPN*CROPN) return;
  int r = i / CROPN, q = i - r*CROPN;
  const float* rc = Oc + (size_t)r*ldo;
  const float* rs = Os + (size_t)r*ldo;
  float ar = 0.f, ai = 0.f;
  for (int cl=0; cl<bc; ++cl){
    int cb = cl*640 + 2*q;
    float re = rc[cb]   - rs[cb+1];
    float im = rc[cb+1] + rs[cb];
    size_t sidx = ((size_t)cl*HH + (160+r))*WW + (77+q);
    float sr = smr[sidx], si = smi[sidx];
    ar += sr*re + si*im;
    ai += sr*im - si*re;
  }
  float dx = deapod_f((float)(r - 160), (float)GX);
  float dy = deapod_f((float)(q - 160), (float)GY);
  out[i] = sqrtf(ar*ar + ai*ai) * dx * dy;
}

// ---------- multi-batch fallback ----------
__global__ void combine(const float* __restrict__ Oc, const float* __restrict__ Os,
                        const float* __restrict__ smr, const float* __restrict__ smi,
                        float* __restrict__ accum, int c0, int bc, int ldo){
  int i = blockIdx.x*256 + threadIdx.x;
  if (i >= CROPN*CROPN) return;
  int r = i / CROPN, q = i - r*CROPN;
  const float* rc = Oc + (size_t)r*ldo;
  const float* rs = Os + (size_t)r*ldo;
  float ar = 0.f, ai = 0.f;
  for (int cl=0; cl<bc; ++cl){
    int cb = cl*640 + 2*q;
    float re = rc[cb]   - rs[cb+1];
    float im = rc[cb+1] + rs[cb];
    size_t sidx = ((size_t)(c0+cl)*HH + (160+r))*WW + (77+q);
    float sr = smr[sidx], si = smi[sidx];
    ar += sr*re + si*im;
    ai += sr*im - si*re;
  }
  accum[2*i] += ar; accum[2*i+1] += ai;
}

__global__ void final_mag(const float* __restrict__ accum, float* __restrict__ out){
  int i = blockIdx.x*256 + threadIdx.x;
  if (i >= CROPN*CROPN) return;
  int r  = i / CROPN;
  int cc = i - r*CROPN;
  float dx = deapod_f((float)(r  - 160), (float)GX);
  float dy = deapod_f((float)(cc - 160), (float)GY);
  float re = accum[2*i], im = accum[2*i+1];
  out[i] = sqrtf(re*re + im*im) * dx * dy;
}

// gather dispatch helper
static void launch_gather(int nb, const float* ydc, const float* wtab, const int2* itab,
                          const int* bstart, const int* bcur, const int* bent,
                          bf16* A1, int c0, hipStream_t stream){
  switch (nb){
    case 1:  tile_gather_mfma<1><<<NTILE,512,0,stream>>>(ydc,wtab,itab,bstart,bcur,bent,A1,c0); break;
    case 2:  tile_gather_mfma<2><<<NTILE,512,0,stream>>>(ydc,wtab,itab,bstart,bcur,bent,A1,c0); break;
    case 3:  tile_gather_mfma<3><<<NTILE,512,0,stream>>>(ydc,wtab,itab,bstart,bcur,bent,A1,c0); break;
    case 4:  tile_gather_mfma<4><<<NTILE,512,0,stream>>>(ydc,wtab,itab,bstart,bcur,bent,A1,c0); break;
    case 5:  tile_gather_mfma<5><<<NTILE,512,0,stream>>>(ydc,wtab,itab,bstart,bcur,bent,A1,c0); break;
    case 6:  tile_gather_mfma<6><<<NTILE,512,0,stream>>>(ydc,wtab,itab,bstart,bcur,bent,A1,c0); break;
    case 7:  tile_gather_mfma<7><<<NTILE,512,0,stream>>>(ydc,wtab,itab,bstart,bcur,bent,A1,c0); break;
    case 8:  tile_gather_mfma<8><<<NTILE,512,0,stream>>>(ydc,wtab,itab,bstart,bcur,bent,A1,c0); break;
    case 9:  tile_gather_mfma<9><<<NTILE,512,0,stream>>>(ydc,wtab,itab,bstart,bcur,bent,A1,c0); break;
    case 10: tile_gather_mfma<10><<<NTILE,512,0,stream>>>(ydc,wtab,itab,bstart,bcur,bent,A1,c0); break;
    case 11: tile_gather_mfma<11><<<NTILE,512,0,stream>>>(ydc,wtab,itab,bstart,bcur,bent,A1,c0); break;
    case 12: tile_gather_mfma<12><<<NTILE,512,0,stream>>>(ydc,wtab,itab,bstart,bcur,bent,A1,c0); break;
    case 13: tile_gather_mfma<13><<<NTILE,512,0,stream>>>(ydc,wtab,itab,bstart,bcur,bent,A1,c0); break;
    case 14: tile_gather_mfma<14><<<NTILE,512,0,stream>>>(ydc,wtab,itab,bstart,bcur,bent,A1,c0); break;
    default: tile_gather_mfma<15><<<NTILE,512,0,stream>>>(ydc,wtab,itab,bstart,bcur,bent,A1,c0); break;
  }
}

extern "C" void kernel_launch(void* const* d_in, const int* in_sizes, int n_in,
                              void* d_out, int out_size, void* d_ws, size_t ws_size,
                              hipStream_t stream){
  const float* kr    = (const float*)d_in[0];
  const float* ki    = (const float*)d_in[1];
  const float* ktraj = (const float*)d_in[2];
  const float* dc    = (const float*)d_in[3];
  const float* smr   = (const float*)d_in[4];
  const float* smi   = (const float*)d_in[5];
  float* out = (float*)d_out;

  // ---- workspace carve (bytes) ----
  const size_t acc_b   = (size_t)CROPN*CROPN*2*4;
  const size_t B1_b    = (size_t)M1*K1F*2;
  const size_t W2_b    = (size_t)M2F*K2F*2;
  const size_t ydc_b   = (size_t)MPTS*NC*2*4;
  const size_t wtab_b  = (size_t)MPTS*12*4;
  const size_t itab_b  = (size_t)MPTS*8;
  const size_t bh_b    = 16384;
  const size_t bent_b  = (size_t)MAXENT*4;
  const size_t fixed_b = acc_b+B1_b+2*W2_b+ydc_b+wtab_b+itab_b+3*bh_b+bent_b;

  const size_t A1_pc   = (size_t)GX*2*K1*2;          // 4,915,200 (A2p+A2m alias)
  const size_t C1_pc   = (size_t)GX*2*M1*2;          // 1,966,080 (Oc+Os alias)
  const size_t percoil = A1_pc + C1_pc;

  int bc = 1;
  if (ws_size > fixed_b + percoil){
    size_t b = (ws_size - fixed_b) / percoil;
    bc = (int)(b > NC ? NC : b);
    if (bc < 1) bc = 1;
  }

  char* p = (char*)d_ws;
  float* accum  = (float*)p; p += acc_b;
  bf16*  B1     = (bf16*)p;  p += B1_b;
  bf16*  W2c    = (bf16*)p;  p += W2_b;
  bf16*  W2s    = (bf16*)p;  p += W2_b;
  float* ydc    = (float*)p; p += ydc_b;
  float* wtab   = (float*)p; p += wtab_b;
  int2*  itab   = (int2*)p;  p += itab_b;
  int*   bhist  = (int*)p;   p += bh_b;
  int*   bstart = (int*)p;   p += bh_b;
  int*   bcur   = (int*)p;   p += bh_b;
  int*   bent   = (int*)p;   p += bent_b;
  bf16*  A1     = (bf16*)p;
  bf16*  A2p    = (bf16*)p;                          // aliases A1 (dead after GEMM1)
  bf16*  A2m    = A2p + (size_t)bc*640*K2F;
  p += (size_t)bc*A1_pc;
  bf16*  C1t    = (bf16*)p;
  float* Oc     = (float*)p;                         // aliases C1t (dead after pack)
  float* Os     = Oc + (size_t)bc*M2F*640;
  p += (size_t)bc*C1_pc;

  // ---- one-time builds ----
  hipMemsetAsync(bhist, 0, NTILE*4, stream);
  prep_gen<<<PREP_BLOCKS + GEN_BLOCKS, 256, 0, stream>>>(kr, ki, dc, ktraj, ydc, wtab,
                                                         itab, bhist, B1, W2c, W2s);
  bin_scan<<<1, 256, 0, stream>>>(bhist, bstart, bcur);
  bin_fill<<<(MPTS+255)/256, 256, 0, stream>>>(itab, bcur, bent);
  if (bc < NC) hipMemsetAsync(accum, 0, acc_b, stream);

  // ---- per coil-batch pipeline ----
  for (int c0 = 0; c0 < NC; c0 += bc){
    int nb = NC - c0; if (nb > bc) nb = bc;
    int ncols = nb*2560;

    launch_gather(nb, ydc, wtab, itab, bstart, bcur, bent, A1, c0, stream);

    // GEMM1 with in-staging ky-fold: K=480, 512 threads/8 waves, trio-XCD-swizzled
    gemm1_fold<<<3*(ncols/BN), 512, 0, stream>>>(B1, A1, C1t, ncols);

    int tot2 = nb*161*80;
    pack_fold<<<(tot2+255)/256, 256, 0, stream>>>(C1t, A2p, A2m, nb, ncols);

    gemm_bt64_2<<<dim3(M2F/64, nb*640/64, 2), 256, 0, stream>>>(W2c, A2p, Oc,
                                                                W2s, A2m, Os,
                                                                K2F, nb*640);

    if (bc >= NC){
      combine_final<<<(CROPN*CROPN+255)/256, 256, 0, stream>>>(Oc, Os, smr, smi, out, nb, nb*640);
    } else {
      combine<<<(CROPN*CROPN+255)/256, 256, 0, stream>>>(Oc, Os, smr, smi, accum, c0, nb, nb*640);
    }
  }
  if (bc < NC)
    final_mag<<<(CROPN*CROPN+255)/256, 256, 0, stream>>>(accum, out);
}

// Round 18
// 157.388 us; speedup vs baseline: 1.0634x; 1.0634x over previous
//
#include <hip/hip_runtime.h>

typedef __bf16 bf16;
typedef __attribute__((ext_vector_type(8))) __bf16 bf16x8;
typedef __attribute__((ext_vector_type(4))) float f32x4;
typedef __attribute__((ext_vector_type(2))) float f32x2;

#define MPTS 40960
#define NC 15
#define GX 1280
#define GY 948
#define HH 640
#define WW 474
#define CROPN 320

#define K1 960    // A1 row width (ky padded 948->960)
#define K1F 480   // folded ky K for GEMM1
#define M1 384    // rows: [0,192)=cos n, [192,384)=sin n
#define K2F 672   // folded kx
#define M2F 320

#define NTX 80
#define NTY 30
#define NTILE (NTX*NTY)   // 2400
#define MAXENT (MPTS*4)
#define CHUNK 128

// ---------- modified Bessel I0 ----------
__device__ __forceinline__ float i0f_dev(float x){
  if (x < 3.75f){
    float t = x*(1.0f/3.75f); t *= t;
    return 1.0f + t*(3.5156229f + t*(3.0899424f + t*(1.2067492f +
                 t*(0.2659732f + t*(0.0360768f + t*0.0045813f)))));
  } else {
    float t = 3.75f/x;
    float p = 0.39894228f + t*(0.01328592f + t*(0.00225319f + t*(-0.00157565f +
              t*(0.00916281f + t*(-0.02057706f + t*(0.02635537f +
              t*(-0.01647633f + t*0.00392377f)))))));
    return __expf(x)*rsqrtf(x)*p;
  }
}

__device__ __forceinline__ float kb_w(float u){
  float a = 1.0f - u*u*(1.0f/9.0f);
  return i0f_dev(14.04f*sqrtf(fmaxf(a, 0.0f)))*(1.0f/6.0f);
}

#define B1_ELEMS (M1*K1F)
#define W2_ELEMS (M2F*K2F)
#define PREP_BLOCKS ((MPTS+255)/256)
#define GEN_BLOCKS  ((B1_ELEMS+W2_ELEMS+255)/256)

// ---------- fused prep (ydc/wtab/itab/hist) + twiddle gen ----------
__global__ void prep_gen(const float* __restrict__ kr, const float* __restrict__ ki,
                         const float* __restrict__ dc, const float* __restrict__ ktraj,
                         float* __restrict__ ydc, float* __restrict__ wtab,
                         int2* __restrict__ itab, int* __restrict__ bhist,
                         bf16* __restrict__ B1, bf16* __restrict__ W2c,
                         bf16* __restrict__ W2s){
  int b = blockIdx.x;
  if (b < PREP_BLOCKS){
    int m = b*256 + threadIdx.x;
    if (m >= MPTS) return;
    float d = dc[m];
    #pragma unroll
    for (int c=0;c<NC;++c){
      ydc[((size_t)m*NC + c)*2    ] = kr[(size_t)c*MPTS + m]*d;
      ydc[((size_t)m*NC + c)*2 + 1] = ki[(size_t)c*MPTS + m]*d;
    }
    const float PI2 = 6.28318530717958647692f;
    float tmx = ktraj[m]        * ((float)GX/PI2);
    float tmy = ktraj[MPTS + m] * ((float)GY/PI2);
    float bx = floorf(tmx - 3.0f), by = floorf(tmy - 3.0f);
    float wx[6], wy[6];
    #pragma unroll
    for (int j=0;j<6;++j){
      wx[j] = kb_w(tmx - (bx + (float)(j+1)));
      wy[j] = kb_w(tmy - (by + (float)(j+1)));
    }
    float4* wt = (float4*)(wtab + (size_t)m*12);
    wt[0] = make_float4(wx[0], wx[1], wx[2], wx[3]);
    wt[1] = make_float4(wx[4], wx[5], wy[0], wy[1]);
    wt[2] = make_float4(wy[2], wy[3], wy[4], wy[5]);
    int ix0 = ((int)bx + 1) % GX; if (ix0 < 0) ix0 += GX;
    int iy0 = ((int)by + 1) % GY; if (iy0 < 0) iy0 += GY;
    itab[m] = make_int2(ix0, iy0);
    int tx0 = ix0 >> 4, tx1 = ((ix0 + 5) % GX) >> 4;
    int ty0 = iy0 >> 5, ty1 = ((iy0 + 5) % GY) >> 5;
    atomicAdd(&bhist[tx0*NTY+ty0],1);
    if (tx1!=tx0) atomicAdd(&bhist[tx1*NTY+ty0],1);
    if (ty1!=ty0){
      atomicAdd(&bhist[tx0*NTY+ty1],1);
      if (tx1!=tx0) atomicAdd(&bhist[tx1*NTY+ty1],1);
    }
    return;
  }
  int i = (b - PREP_BLOCKS)*256 + threadIdx.x;
  if (i < B1_ELEMS){
    int r = i / K1F, k = i - r*K1F;
    float v = 0.f;
    if (k <= 474){
      if (r < 192){
        int n = r;
        if (n <= 160){
          int rem = (k * n) % GY;
          float ang = 6.28318530717958647692f * (float)rem / (float)GY;
          float s, c; sincosf(ang, &s, &c); v = c;
        }
      } else {
        int n = r - 192;
        if (n >= 1 && n <= 160){
          int rem = (k * n) % GY;
          float ang = 6.28318530717958647692f * (float)rem / (float)GY;
          float s, c; sincosf(ang, &s, &c); v = s;
        }
      }
    }
    B1[i] = (bf16)v;
  } else if (i < B1_ELEMS + W2_ELEMS){
    int j = i - B1_ELEMS;
    int r = j / K2F, k = j - r*K2F;
    int nx = (r < 160) ? (1120 + r) : (r - 160);
    float vc = 0.f, vs = 0.f;
    if (k < 640){
      int rem = (k * nx) % GX;
      float ang = 6.28318530717958647692f * (float)rem / (float)GX;
      float s, c; sincosf(ang, &s, &c);
      vc = c; vs = s;
    } else if (k == 640){
      vc = (nx & 1) ? -1.f : 1.f; vs = 0.f;
    }
    W2c[j] = (bf16)vc;
    W2s[j] = (bf16)vs;
  }
}

#define SCAN_PER 10
__global__ __launch_bounds__(256) void bin_scan(const int* __restrict__ bhist,
                                                int* __restrict__ bstart,
                                                int* __restrict__ bcur){
  __shared__ int ps[256];
  int t = threadIdx.x;
  int v[SCAN_PER]; int s = 0;
  #pragma unroll
  for (int j=0;j<SCAN_PER;++j){ int i = t*SCAN_PER+j; v[j] = (i<NTILE)?bhist[i]:0; s += v[j]; }
  ps[t] = s; __syncthreads();
  for (int off=1; off<256; off<<=1){
    int x = (t>=off) ? ps[t-off] : 0;
    __syncthreads();
    ps[t] += x;
    __syncthreads();
  }
  int run = (t==0) ? 0 : ps[t-1];
  #pragma unroll
  for (int j=0;j<SCAN_PER;++j){
    int i = t*SCAN_PER+j;
    if (i<NTILE){ bstart[i]=run; bcur[i]=run; }
    run += v[j];
  }
}

__global__ void bin_fill(const int2* __restrict__ itab, int* __restrict__ bcur,
                         int* __restrict__ bent){
  int m = blockIdx.x*256 + threadIdx.x;
  if (m >= MPTS) return;
  int2 ii = itab[m];
  int tx0 = ii.x >> 4, tx1 = ((ii.x + 5) % GX) >> 4;
  int ty0 = ii.y >> 5, ty1 = ((ii.y + 5) % GY) >> 5;
  int p = atomicAdd(&bcur[tx0*NTY+ty0],1); bent[p] = m;
  if (tx1!=tx0){ p = atomicAdd(&bcur[tx1*NTY+ty0],1); bent[p] = m; }
  if (ty1!=ty0){
    p = atomicAdd(&bcur[tx0*NTY+ty1],1); bent[p] = m;
    if (tx1!=tx0){ p = atomicAdd(&bcur[tx1*NTY+ty1],1); bent[p] = m; }
  }
}

// ---------- tile gather: 16x32 tile, 512 threads, 1 cell/thread, packed f32x2 FMA ----------
template<int BC>
__global__ __launch_bounds__(512, 4) void tile_gather(const float* __restrict__ ydc,
                                                      const float* __restrict__ wtab,
                                                      const int2* __restrict__ itab,
                                                      const int* __restrict__ bstart,
                                                      const int* __restrict__ bend,
                                                      const int* __restrict__ bent,
                                                      bf16* __restrict__ A1, int c0){
  int tile = blockIdx.x;
  int tx = tile / NTY, ty = tile - tx*NTY;
  int x0 = tx*16, y0 = ty*32;
  int t = threadIdx.x;
  int kxl = t >> 5;
  int kyl = t & 31;
  int kxi = x0 + kxl;
  int kyi = y0 + kyl;

  __shared__ float swx[CHUNK][6], swy[CHUNK][6];
  __shared__ float sy[CHUNK][2*BC];    // row stride 2*BC*4 B (120 B for BC=15, 8B-aligned)
  __shared__ int   six0[CHUNK], siy0[CHUNK];

  f32x2 accv[BC];
  #pragma unroll
  for (int c=0;c<BC;++c){ accv[c] = (f32x2){0.f, 0.f}; }

  int beg = bstart[tile], end = bend[tile];
  for (int s0 = beg; s0 < end; s0 += CHUNK){
    int ns = end - s0; if (ns > CHUNK) ns = CHUNK;
    __syncthreads();
    for (int i=t; i<ns; i+=512){
      int m = bent[s0+i];
      const float4* wt = (const float4*)(wtab + (size_t)m*12);
      float4 w0 = wt[0], w1 = wt[1], w2 = wt[2];
      swx[i][0]=w0.x; swx[i][1]=w0.y; swx[i][2]=w0.z; swx[i][3]=w0.w;
      swx[i][4]=w1.x; swx[i][5]=w1.y;
      swy[i][0]=w1.z; swy[i][1]=w1.w; swy[i][2]=w2.x; swy[i][3]=w2.y;
      swy[i][4]=w2.z; swy[i][5]=w2.w;
      int2 ii = itab[m];
      six0[i] = ii.x; siy0[i] = ii.y;
    }
    for (int i=t; i<ns*2*BC; i+=512){
      int s = i / (2*BC), f = i - s*(2*BC);
      sy[s][f] = ydc[((size_t)bent[s0+s]*NC + c0)*2 + f];
    }
    __syncthreads();
    for (int s=0; s<ns; ++s){
      int lx = kxi - six0[s]; if (lx < 0) lx += GX;
      if (lx < 6){
        int ly = kyi - siy0[s]; if (ly < 0) ly += GY;
        float w = (ly < 6) ? swx[s][lx] * swy[s][ly] : 0.0f;
        f32x2 wv = (f32x2){w, w};
        const f32x2* syv = (const f32x2*)&sy[s][0];
        #pragma unroll
        for (int c=0;c<BC;++c){
          accv[c] += wv * syv[c];      // v_pk_fma_f32 + ds_read_b64
        }
      }
    }
  }

  float mask = (kyi < GY) ? 1.0f : 0.0f;
  #pragma unroll
  for (int c=0;c<BC;++c){
    size_t base = ((size_t)((c*GX + kxi)*2)) * K1;
    A1[base + kyi]      = (bf16)(accv[c][0]*mask);
    A1[base + K1 + kyi] = (bf16)(accv[c][1]*mask);
  }
}

// ---------- GEMM1 with in-staging ky-fold, 512 threads / 8 waves (R16 known-good) ----------
#define BM 128
#define BN 128
#define BK 32
#define LDT 40

__device__ __forceinline__ void fold8(bf16x8 own, bf16x8 mA, bf16x8 mB, int k0,
                                      bf16x8& pv, bf16x8& mv){
  float mir[8];
  mir[0]=(float)mB[4]; mir[1]=(float)mB[3]; mir[2]=(float)mB[2]; mir[3]=(float)mB[1];
  mir[4]=(float)mB[0]; mir[5]=(float)mA[7]; mir[6]=(float)mA[6]; mir[7]=(float)mA[5];
  #pragma unroll
  for (int j=0;j<8;++j){
    float mm = (k0 + j == 474) ? 0.f : mir[j];
    float ov = (float)own[j];
    pv[j] = (bf16)(ov + mm);
    mv[j] = (bf16)(ov - mm);
  }
}

__global__ __launch_bounds__(512) void gemm1_fold(const bf16* __restrict__ A,
                                                  const bf16* __restrict__ B,
                                                  bf16* __restrict__ C,
                                                  int ldc){
  int total = gridDim.x;
  int qq = total >> 3, rr = total & 7;
  int d = blockIdx.x;
  int xcd = d & 7, jj = d >> 3;
  int L = (xcd < rr) ? (xcd*(qq+1) + jj) : (rr*(qq+1) + (xcd-rr)*qq + jj);
  size_t tileM = (size_t)(L % 3) * BM;
  size_t tileN = (size_t)(L / 3) * BN;

  __shared__ bf16 As[BM*LDT];
  __shared__ bf16 Bp[BM*LDT];
  __shared__ bf16 Bm[BM*LDT];
  int t = threadIdx.x;
  int lane = t & 63;
  int wave = t >> 6;
  int wm = wave >> 2, wn = wave & 3;
  bool isCos = (tileM + (size_t)wm*64) < 192;

  f32x4 zero = {0.f, 0.f, 0.f, 0.f};
  f32x4 acc[4][2];
  #pragma unroll
  for (int m=0;m<4;++m)
    #pragma unroll
    for (int n=0;n<2;++n) acc[m][n] = zero;

  int r0 = t >> 2;
  int kc = (t & 3) * 8;
  const bf16* Arow = A + (tileM + r0) * (size_t)K1F + kc;
  const bf16* Brow = B + (tileN + r0) * (size_t)K1;

  bf16x8 a0  = *(const bf16x8*)(Arow);
  bf16x8 o0  = *(const bf16x8*)(Brow + kc);
  bf16x8 mA0 = *(const bf16x8*)(Brow + 936 - kc);
  bf16x8 mB0 = *(const bf16x8*)(Brow + 944 - kc);

  int lr = lane & 15, lk = (lane >> 4) * 8;

  for (int kt = 0; kt < K1F; kt += BK){
    bf16x8 p0, m0;
    fold8(o0, mA0, mB0, kt + kc, p0, m0);
    __syncthreads();
    *(bf16x8*)(As + r0*LDT + kc) = a0;
    *(bf16x8*)(Bp + r0*LDT + kc) = p0;
    *(bf16x8*)(Bm + r0*LDT + kc) = m0;
    __syncthreads();

    if (kt + BK < K1F){
      int kn = kt + BK + kc;
      a0  = *(const bf16x8*)(Arow + kt + BK);
      o0  = *(const bf16x8*)(Brow + kn);
      mA0 = *(const bf16x8*)(Brow + 936 - kn);
      mB0 = *(const bf16x8*)(Brow + 944 - kn);
    }

    const bf16* Bsel = isCos ? Bp : Bm;
    bf16x8 af[4], bg[2];
    #pragma unroll
    for (int m=0;m<4;++m)
      af[m] = *(const bf16x8*)(As + (wm*64 + m*16 + lr)*LDT + lk);
    #pragma unroll
    for (int n=0;n<2;++n)
      bg[n] = *(const bf16x8*)(Bsel + (wn*32 + n*16 + lr)*LDT + lk);
    #pragma unroll
    for (int m=0;m<4;++m)
      #pragma unroll
      for (int n=0;n<2;++n)
        acc[m][n] = __builtin_amdgcn_mfma_f32_16x16x32_bf16(af[m], bg[n], acc[m][n], 0, 0, 0);
  }

  int lrow = (lane >> 4) * 4;
  #pragma unroll
  for (int m=0;m<4;++m)
    #pragma unroll
    for (int n=0;n<2;++n){
      size_t row = tileM + wm*64 + m*16 + lrow;
      size_t col = tileN + wn*32 + n*16 + lr;
      #pragma unroll
      for (int r2=0;r2<4;++r2)
        C[(row + r2)*(size_t)ldc + col] = (bf16)acc[m][n][r2];
    }
}

// ---------- pack C1t(bf16) -> folded A2p/A2m (cos row n; sin row 192+n) ----------
__global__ void pack_fold(const bf16* __restrict__ C1t, bf16* __restrict__ A2p,
                          bf16* __restrict__ A2m, int nb, int ldc1){
  int i = blockIdx.x*256 + threadIdx.x;
  if (i >= nb*161*80) return;
  int kxg = i % 80;
  int rem = i / 80;
  int n   = rem % 161;
  int cl  = rem / 161;
  int kx0 = kxg*8;

  const bf16* rowC = C1t + (size_t)n*ldc1;
  const bf16* rowS = C1t + (size_t)(192+n)*ldc1;
  int ob = cl*2560 + kx0*2;
  int mb = 1280 - kx0 - 8;
  int mbb = cl*2560 + mb*2;

  float CRo[8], CIo[8], SRo[8], SIo[8];
  {
    bf16x8 c0 = *(const bf16x8*)(rowC + ob);
    bf16x8 c1 = *(const bf16x8*)(rowC + ob + 8);
    bf16x8 s0 = *(const bf16x8*)(rowS + ob);
    bf16x8 s1 = *(const bf16x8*)(rowS + ob + 8);
    #pragma unroll
    for (int j=0;j<4;++j){
      CRo[j]   = (float)c0[2*j]; CIo[j]   = (float)c0[2*j+1];
      CRo[j+4] = (float)c1[2*j]; CIo[j+4] = (float)c1[2*j+1];
      SRo[j]   = (float)s0[2*j]; SIo[j]   = (float)s0[2*j+1];
      SRo[j+4] = (float)s1[2*j]; SIo[j+4] = (float)s1[2*j+1];
    }
  }
  float CRm[16], CIm[16], SRm[16], SIm[16];
  {
    #pragma unroll
    for (int h=0;h<4;++h){
      bf16x8 cm = *(const bf16x8*)(rowC + mbb + 8*h);
      bf16x8 sm = *(const bf16x8*)(rowS + mbb + 8*h);
      #pragma unroll
      for (int j=0;j<4;++j){
        CRm[h*4+j] = (float)cm[2*j]; CIm[h*4+j] = (float)cm[2*j+1];
        SRm[h*4+j] = (float)sm[2*j]; SIm[h*4+j] = (float)sm[2*j+1];
      }
    }
  }

  #pragma unroll
  for (int br=0; br<2; ++br){
    bool valid = (br==0) ? (n <= 159) : (n >= 1);
    if (!valid) continue;
    int qv = (br==0) ? (160+n) : (160-n);
    bf16x8 pre, mre, pim, mim;
    #pragma unroll
    for (int j=0;j<8;++j){
      float tro, tio, trm, tim_;
      if (br==0){ tro = CRo[j]-SIo[j]; tio = SRo[j]+CIo[j]; }
      else      { tro = CRo[j]+SIo[j]; tio = CIo[j]-SRo[j]; }
      int mi = 8 - j;
      if (br==0){ trm = CRm[mi]-SIm[mi]; tim_ = SRm[mi]+CIm[mi]; }
      else      { trm = CRm[mi]+SIm[mi]; tim_ = CIm[mi]-SRm[mi]; }
      if (j==0 && kxg==0){ trm = 0.f; tim_ = 0.f; }
      pre[j] = (bf16)(tro + trm); mre[j] = (bf16)(tro - trm);
      pim[j] = (bf16)(tio + tim_); mim[j] = (bf16)(tio - tim_);
    }
    size_t r0 = ((size_t)(cl*640 + 2*qv))*K2F;
    *(bf16x8*)(A2p + r0 + kx0)        = pre;
    *(bf16x8*)(A2m + r0 + kx0)        = mre;
    *(bf16x8*)(A2p + r0 + K2F + kx0)  = pim;
    *(bf16x8*)(A2m + r0 + K2F + kx0)  = mim;
    if (kxg == 0){
      bf16x8 c6 = *(const bf16x8*)(rowC + cl*2560 + 1280);
      bf16x8 s6 = *(const bf16x8*)(rowS + cl*2560 + 1280);
      float CR6 = (float)c6[0], CI6 = (float)c6[1];
      float SR6 = (float)s6[0], SI6 = (float)s6[1];
      float t6re, t6im;
      if (br==0){ t6re = CR6-SI6; t6im = SR6+CI6; }
      else      { t6re = CR6+SI6; t6im = CI6-SR6; }
      A2p[r0 + 640]       = (bf16)t6re;
      A2p[r0 + K2F + 640] = (bf16)t6im;
      A2m[r0 + 640]       = (bf16)0.f;
      A2m[r0 + K2F + 640] = (bf16)0.f;
    }
  }
}

// ---------- bf16 GEMM, 64x64 tile, fp32 C, both folds in one launch ----------
__global__ __launch_bounds__(256) void gemm_bt64_2(const bf16* __restrict__ Acos,
                                                   const bf16* __restrict__ Bcos,
                                                   float* __restrict__ Ccos,
                                                   const bf16* __restrict__ Asin,
                                                   const bf16* __restrict__ Bsin,
                                                   float* __restrict__ Csin,
                                                   int K, int ldc){
  const bf16* A = blockIdx.z ? Asin : Acos;
  const bf16* B = blockIdx.z ? Bsin : Bcos;
  float*      C = blockIdx.z ? Csin : Ccos;

  __shared__ bf16 As[64*LDT];
  __shared__ bf16 Bs[64*LDT];
  int t = threadIdx.x;
  int lane = t & 63;
  int wave = t >> 6;
  int wm = wave >> 1, wn = wave & 1;
  size_t tileM = (size_t)blockIdx.x * 64;
  size_t tileN = (size_t)blockIdx.y * 64;

  const bf16* Ab = A + tileM * K;
  const bf16* Bb = B + tileN * K;

  f32x4 zero = {0.f, 0.f, 0.f, 0.f};
  f32x4 acc[2][2];
  #pragma unroll
  for (int m=0;m<2;++m)
    #pragma unroll
    for (int n=0;n<2;++n) acc[m][n] = zero;

  int r0 = t >> 2;
  int kc = (t & 3) * 8;
  size_t aoff = (size_t)r0 * K + kc;

  bf16x8 a0 = *(const bf16x8*)(Ab + aoff);
  bf16x8 b0 = *(const bf16x8*)(Bb + aoff);

  int lr = lane & 15, lk = (lane >> 4) * 8;

  for (int kt = 0; kt < K; kt += BK){
    __syncthreads();
    *(bf16x8*)(As + r0*LDT + kc) = a0;
    *(bf16x8*)(Bs + r0*LDT + kc) = b0;
    __syncthreads();

    bool more = (kt + BK) < K;
    if (more){
      size_t o = aoff + kt + BK;
      a0 = *(const bf16x8*)(Ab + o);
      b0 = *(const bf16x8*)(Bb + o);
    }

    bf16x8 af[2], bg[2];
    #pragma unroll
    for (int m=0;m<2;++m)
      af[m] = *(const bf16x8*)(As + (wm*32 + m*16 + lr)*LDT + lk);
    #pragma unroll
    for (int n=0;n<2;++n)
      bg[n] = *(const bf16x8*)(Bs + (wn*32 + n*16 + lr)*LDT + lk);
    #pragma unroll
    for (int m=0;m<2;++m)
      #pragma unroll
      for (int n=0;n<2;++n)
        acc[m][n] = __builtin_amdgcn_mfma_f32_16x16x32_bf16(af[m], bg[n], acc[m][n], 0, 0, 0);
  }

  int lrow = (lane >> 4) * 4;
  #pragma unroll
  for (int m=0;m<2;++m)
    #pragma unroll
    for (int n=0;n<2;++n){
      size_t row = tileM + wm*32 + m*16 + lrow;
      size_t col = tileN + wn*32 + n*16 + lr;
      #pragma unroll
      for (int r=0;r<4;++r)
        C[(row + r)*(size_t)ldc + col] = acc[m][n][r];
    }
}

// ---------- deapodization ----------
__device__ __forceinline__ float deapod_f(float n, float G){
  float x = 3.14159265358979323846f * 6.0f * n / G;
  float z = 197.1216f - x*x;
  float sz = sqrtf(fabsf(z) + 1e-12f);
  float K;
  if (z > 0.0f){
    float e = __expf(sz);
    K = (e - 1.0f/e)*0.5f/sz;
  } else {
    K = __sinf(sz)/sz;
  }
  return 1.0f/K;
}

// ---------- fused coil combine + deapod + magnitude (single-batch path) ----------
__global__ void combine_final(const float* __restrict__ Oc, const float* __restrict__ Os,
                              const float* __restrict__ smr, const float* __restrict__ smi,
                              float* __restrict__ out, int bc, int ldo){
  int i = blockIdx.x*256 + threadIdx.x;
  if (i >= CROPN*CROPN) return;
  int r = i / CROPN, q = i - r*CROPN;
  const float* rc = Oc + (size_t)r*ldo;
  const float* rs = Os + (size_t)r*ldo;
  float ar = 0.f, ai = 0.f;
  for (int cl=0; cl<bc; ++cl){
    int cb = cl*640 + 2*q;
    float re = rc[cb]   - rs[cb+1];
    float im = rc[cb+1] + rs[cb];
    size_t sidx = ((size_t)cl*HH + (160+r))*WW + (77+q);
    float sr = smr[sidx], si = smi[sidx];
    ar += sr*re + si*im;
    ai += sr*im - si*re;
  }
  float dx = deapod_f((float)(r - 160), (float)GX);
  float dy = deapod_f((float)(q - 160), (float)GY);
  out[i] = sqrtf(ar*ar + ai*ai) * dx * dy;
}

// ---------- multi-batch fallback ----------
__global__ void combine(const float* __restrict__ Oc, const float* __restrict__ Os,
                        const float* __restrict__ smr, const float* __restrict__ smi,
                        float* __restrict__ accum, int c0, int bc, int ldo){
  int i = blockIdx.x*256 + threadIdx.x;
  if (i >= CROPN*CROPN) return;
  int r = i / CROPN, q = i - r*CROPN;
  const float* rc = Oc + (size_t)r*ldo;
  const float* rs = Os + (size_t)r*ldo;
  float ar = 0.f, ai = 0.f;
  for (int cl=0; cl<bc; ++cl){
    int cb = cl*640 + 2*q;
    float re = rc[cb]   - rs[cb+1];
    float im = rc[cb+1] + rs[cb];
    size_t sidx = ((size_t)(c0+cl)*HH + (160+r))*WW + (77+q);
    float sr = smr[sidx], si = smi[sidx];
    ar += sr*re + si*im;
    ai += sr*im - si*re;
  }
  accum[2*i] += ar; accum[2*i+1] += ai;
}

__global__ void final_mag(const float* __restrict__ accum, float* __restrict__ out){
  int i = blockIdx.x*256 + threadIdx.x;
  if (i >= CROPN*CROPN) return;
  int r  = i / CROPN;
  int cc = i - r*CROPN;
  float dx = deapod_f((float)(r  - 160), (float)GX);
  float dy = deapod_f((float)(cc - 160), (float)GY);
  float re = accum[2*i], im = accum[2*i+1];
  out[i] = sqrtf(re*re + im*im) * dx * dy;
}

// gather dispatch helper
static void launch_gather(int nb, const float* ydc, const float* wtab, const int2* itab,
                          const int* bstart, const int* bcur, const int* bent,
                          bf16* A1, int c0, hipStream_t stream){
  switch (nb){
    case 1:  tile_gather<1><<<NTILE,512,0,stream>>>(ydc,wtab,itab,bstart,bcur,bent,A1,c0); break;
    case 2:  tile_gather<2><<<NTILE,512,0,stream>>>(ydc,wtab,itab,bstart,bcur,bent,A1,c0); break;
    case 3:  tile_gather<3><<<NTILE,512,0,stream>>>(ydc,wtab,itab,bstart,bcur,bent,A1,c0); break;
    case 4:  tile_gather<4><<<NTILE,512,0,stream>>>(ydc,wtab,itab,bstart,bcur,bent,A1,c0); break;
    case 5:  tile_gather<5><<<NTILE,512,0,stream>>>(ydc,wtab,itab,bstart,bcur,bent,A1,c0); break;
    case 6:  tile_gather<6><<<NTILE,512,0,stream>>>(ydc,wtab,itab,bstart,bcur,bent,A1,c0); break;
    case 7:  tile_gather<7><<<NTILE,512,0,stream>>>(ydc,wtab,itab,bstart,bcur,bent,A1,c0); break;
    case 8:  tile_gather<8><<<NTILE,512,0,stream>>>(ydc,wtab,itab,bstart,bcur,bent,A1,c0); break;
    case 9:  tile_gather<9><<<NTILE,512,0,stream>>>(ydc,wtab,itab,bstart,bcur,bent,A1,c0); break;
    case 10: tile_gather<10><<<NTILE,512,0,stream>>>(ydc,wtab,itab,bstart,bcur,bent,A1,c0); break;
    case 11: tile_gather<11><<<NTILE,512,0,stream>>>(ydc,wtab,itab,bstart,bcur,bent,A1,c0); break;
    case 12: tile_gather<12><<<NTILE,512,0,stream>>>(ydc,wtab,itab,bstart,bcur,bent,A1,c0); break;
    case 13: tile_gather<13><<<NTILE,512,0,stream>>>(ydc,wtab,itab,bstart,bcur,bent,A1,c0); break;
    case 14: tile_gather<14><<<NTILE,512,0,stream>>>(ydc,wtab,itab,bstart,bcur,bent,A1,c0); break;
    default: tile_gather<15><<<NTILE,512,0,stream>>>(ydc,wtab,itab,bstart,bcur,bent,A1,c0); break;
  }
}

extern "C" void kernel_launch(void* const* d_in, const int* in_sizes, int n_in,
                              void* d_out, int out_size, void* d_ws, size_t ws_size,
                              hipStream_t stream){
  const float* kr    = (const float*)d_in[0];
  const float* ki    = (const float*)d_in[1];
  const float* ktraj = (const float*)d_in[2];
  const float* dc    = (const float*)d_in[3];
  const float* smr   = (const float*)d_in[4];
  const float* smi   = (const float*)d_in[5];
  float* out = (float*)d_out;

  // ---- workspace carve (bytes) ----
  const size_t acc_b   = (size_t)CROPN*CROPN*2*4;
  const size_t B1_b    = (size_t)M1*K1F*2;
  const size_t W2_b    = (size_t)M2F*K2F*2;
  const size_t ydc_b   = (size_t)MPTS*NC*2*4;
  const size_t wtab_b  = (size_t)MPTS*12*4;
  const size_t itab_b  = (size_t)MPTS*8;
  const size_t bh_b    = 16384;
  const size_t bent_b  = (size_t)MAXENT*4;
  const size_t fixed_b = acc_b+B1_b+2*W2_b+ydc_b+wtab_b+itab_b+3*bh_b+bent_b;

  const size_t A1_pc   = (size_t)GX*2*K1*2;          // 4,915,200 (A2p+A2m alias)
  const size_t C1_pc   = (size_t)GX*2*M1*2;          // 1,966,080 (Oc+Os alias)
  const size_t percoil = A1_pc + C1_pc;

  int bc = 1;
  if (ws_size > fixed_b + percoil){
    size_t b = (ws_size - fixed_b) / percoil;
    bc = (int)(b > NC ? NC : b);
    if (bc < 1) bc = 1;
  }

  char* p = (char*)d_ws;
  float* accum  = (float*)p; p += acc_b;
  bf16*  B1     = (bf16*)p;  p += B1_b;
  bf16*  W2c    = (bf16*)p;  p += W2_b;
  bf16*  W2s    = (bf16*)p;  p += W2_b;
  float* ydc    = (float*)p; p += ydc_b;
  float* wtab   = (float*)p; p += wtab_b;
  int2*  itab   = (int2*)p;  p += itab_b;
  int*   bhist  = (int*)p;   p += bh_b;
  int*   bstart = (int*)p;   p += bh_b;
  int*   bcur   = (int*)p;   p += bh_b;
  int*   bent   = (int*)p;   p += bent_b;
  bf16*  A1     = (bf16*)p;
  bf16*  A2p    = (bf16*)p;                          // aliases A1 (dead after GEMM1)
  bf16*  A2m    = A2p + (size_t)bc*640*K2F;
  p += (size_t)bc*A1_pc;
  bf16*  C1t    = (bf16*)p;
  float* Oc     = (float*)p;                         // aliases C1t (dead after pack)
  float* Os     = Oc + (size_t)bc*M2F*640;
  p += (size_t)bc*C1_pc;

  // ---- one-time builds ----
  hipMemsetAsync(bhist, 0, NTILE*4, stream);
  prep_gen<<<PREP_BLOCKS + GEN_BLOCKS, 256, 0, stream>>>(kr, ki, dc, ktraj, ydc, wtab,
                                                         itab, bhist, B1, W2c, W2s);
  bin_scan<<<1, 256, 0, stream>>>(bhist, bstart, bcur);
  bin_fill<<<(MPTS+255)/256, 256, 0, stream>>>(itab, bcur, bent);
  if (bc < NC) hipMemsetAsync(accum, 0, acc_b, stream);

  // ---- per coil-batch pipeline ----
  for (int c0 = 0; c0 < NC; c0 += bc){
    int nb = NC - c0; if (nb > bc) nb = bc;
    int ncols = nb*2560;

    launch_gather(nb, ydc, wtab, itab, bstart, bcur, bent, A1, c0, stream);

    // GEMM1 with in-staging ky-fold: K=480, 512 threads/8 waves, trio-XCD-swizzled
    gemm1_fold<<<3*(ncols/BN), 512, 0, stream>>>(B1, A1, C1t, ncols);

    int tot2 = nb*161*80;
    pack_fold<<<(tot2+255)/256, 256, 0, stream>>>(C1t, A2p, A2m, nb, ncols);

    gemm_bt64_2<<<dim3(M2F/64, nb*640/64, 2), 256, 0, stream>>>(W2c, A2p, Oc,
                                                                W2s, A2m, Os,
                                                                K2F, nb*640);

    if (bc >= NC){
      combine_final<<<(CROPN*CROPN+255)/256, 256, 0, stream>>>(Oc, Os, smr, smi, out, nb, nb*640);
    } else {
      combine<<<(CROPN*CROPN+255)/256, 256, 0, stream>>>(Oc, Os, smr, smi, accum, c0, nb, nb*640);
    }
  }
  if (bc < NC)
    final_mag<<<(CROPN*CROPN+255)/256, 256, 0, stream>>>(accum, out);
}

// Round 19
// 153.110 us; speedup vs baseline: 1.0931x; 1.0279x over previous
//
#include <hip/hip_runtime.h>

typedef __bf16 bf16;
typedef __attribute__((ext_vector_type(8))) __bf16 bf16x8;
typedef __attribute__((ext_vector_type(4))) float f32x4;
typedef __attribute__((ext_vector_type(2))) float f32x2;

#define MPTS 40960
#define NC 15
#define GX 1280
#define GY 948
#define HH 640
#define WW 474
#define CROPN 320

#define K1 960    // A1 row width (ky padded 948->960)
#define K1F 480   // folded ky K for GEMM1
#define M1 384    // rows: [0,192)=cos n, [192,384)=sin n
#define K2F 672   // folded kx
#define M2F 320

#define NTX 80
#define NTY 30
#define NTILE (NTX*NTY)   // 2400
#define MAXENT (MPTS*4)
#define CHUNK 128

// ---------- modified Bessel I0 ----------
__device__ __forceinline__ float i0f_dev(float x){
  if (x < 3.75f){
    float t = x*(1.0f/3.75f); t *= t;
    return 1.0f + t*(3.5156229f + t*(3.0899424f + t*(1.2067492f +
                 t*(0.2659732f + t*(0.0360768f + t*0.0045813f)))));
  } else {
    float t = 3.75f/x;
    float p = 0.39894228f + t*(0.01328592f + t*(0.00225319f + t*(-0.00157565f +
              t*(0.00916281f + t*(-0.02057706f + t*(0.02635537f +
              t*(-0.01647633f + t*0.00392377f)))))));
    return __expf(x)*rsqrtf(x)*p;
  }
}

__device__ __forceinline__ float kb_w(float u){
  float a = 1.0f - u*u*(1.0f/9.0f);
  return i0f_dev(14.04f*sqrtf(fmaxf(a, 0.0f)))*(1.0f/6.0f);
}

#define B1_ELEMS (M1*K1F)
#define W2_ELEMS (M2F*K2F)
#define PREP_BLOCKS ((MPTS+255)/256)
#define GEN_BLOCKS  ((B1_ELEMS+W2_ELEMS+255)/256)

// ---------- fused prep (ydc/wtab/itab/hist) + twiddle gen ----------
__global__ void prep_gen(const float* __restrict__ kr, const float* __restrict__ ki,
                         const float* __restrict__ dc, const float* __restrict__ ktraj,
                         float* __restrict__ ydc, float* __restrict__ wtab,
                         int2* __restrict__ itab, int* __restrict__ bhist,
                         bf16* __restrict__ B1, bf16* __restrict__ W2c,
                         bf16* __restrict__ W2s){
  int b = blockIdx.x;
  if (b < PREP_BLOCKS){
    int m = b*256 + threadIdx.x;
    if (m >= MPTS) return;
    float d = dc[m];
    #pragma unroll
    for (int c=0;c<NC;++c){
      ydc[((size_t)m*NC + c)*2    ] = kr[(size_t)c*MPTS + m]*d;
      ydc[((size_t)m*NC + c)*2 + 1] = ki[(size_t)c*MPTS + m]*d;
    }
    const float PI2 = 6.28318530717958647692f;
    float tmx = ktraj[m]        * ((float)GX/PI2);
    float tmy = ktraj[MPTS + m] * ((float)GY/PI2);
    float bx = floorf(tmx - 3.0f), by = floorf(tmy - 3.0f);
    float wx[6], wy[6];
    #pragma unroll
    for (int j=0;j<6;++j){
      wx[j] = kb_w(tmx - (bx + (float)(j+1)));
      wy[j] = kb_w(tmy - (by + (float)(j+1)));
    }
    float4* wt = (float4*)(wtab + (size_t)m*12);
    wt[0] = make_float4(wx[0], wx[1], wx[2], wx[3]);
    wt[1] = make_float4(wx[4], wx[5], wy[0], wy[1]);
    wt[2] = make_float4(wy[2], wy[3], wy[4], wy[5]);
    int ix0 = ((int)bx + 1) % GX; if (ix0 < 0) ix0 += GX;
    int iy0 = ((int)by + 1) % GY; if (iy0 < 0) iy0 += GY;
    itab[m] = make_int2(ix0, iy0);
    int tx0 = ix0 >> 4, tx1 = ((ix0 + 5) % GX) >> 4;
    int ty0 = iy0 >> 5, ty1 = ((iy0 + 5) % GY) >> 5;
    atomicAdd(&bhist[tx0*NTY+ty0],1);
    if (tx1!=tx0) atomicAdd(&bhist[tx1*NTY+ty0],1);
    if (ty1!=ty0){
      atomicAdd(&bhist[tx0*NTY+ty1],1);
      if (tx1!=tx0) atomicAdd(&bhist[tx1*NTY+ty1],1);
    }
    return;
  }
  int i = (b - PREP_BLOCKS)*256 + threadIdx.x;
  if (i < B1_ELEMS){
    int r = i / K1F, k = i - r*K1F;
    float v = 0.f;
    if (k <= 474){
      if (r < 192){
        int n = r;
        if (n <= 160){
          int rem = (k * n) % GY;
          float ang = 6.28318530717958647692f * (float)rem / (float)GY;
          float s, c; sincosf(ang, &s, &c); v = c;
        }
      } else {
        int n = r - 192;
        if (n >= 1 && n <= 160){
          int rem = (k * n) % GY;
          float ang = 6.28318530717958647692f * (float)rem / (float)GY;
          float s, c; sincosf(ang, &s, &c); v = s;
        }
      }
    }
    B1[i] = (bf16)v;
  } else if (i < B1_ELEMS + W2_ELEMS){
    int j = i - B1_ELEMS;
    int r = j / K2F, k = j - r*K2F;
    int nx = (r < 160) ? (1120 + r) : (r - 160);
    float vc = 0.f, vs = 0.f;
    if (k < 640){
      int rem = (k * nx) % GX;
      float ang = 6.28318530717958647692f * (float)rem / (float)GX;
      float s, c; sincosf(ang, &s, &c);
      vc = c; vs = s;
    } else if (k == 640){
      vc = (nx & 1) ? -1.f : 1.f; vs = 0.f;
    }
    W2c[j] = (bf16)vc;
    W2s[j] = (bf16)vs;
  }
}

#define SCAN_PER 10
__global__ __launch_bounds__(256) void bin_scan(const int* __restrict__ bhist,
                                                int* __restrict__ bstart,
                                                int* __restrict__ bcur){
  __shared__ int ps[256];
  int t = threadIdx.x;
  int v[SCAN_PER]; int s = 0;
  #pragma unroll
  for (int j=0;j<SCAN_PER;++j){ int i = t*SCAN_PER+j; v[j] = (i<NTILE)?bhist[i]:0; s += v[j]; }
  ps[t] = s; __syncthreads();
  for (int off=1; off<256; off<<=1){
    int x = (t>=off) ? ps[t-off] : 0;
    __syncthreads();
    ps[t] += x;
    __syncthreads();
  }
  int run = (t==0) ? 0 : ps[t-1];
  #pragma unroll
  for (int j=0;j<SCAN_PER;++j){
    int i = t*SCAN_PER+j;
    if (i<NTILE){ bstart[i]=run; bcur[i]=run; }
    run += v[j];
  }
}

__global__ void bin_fill(const int2* __restrict__ itab, int* __restrict__ bcur,
                         int* __restrict__ bent){
  int m = blockIdx.x*256 + threadIdx.x;
  if (m >= MPTS) return;
  int2 ii = itab[m];
  int tx0 = ii.x >> 4, tx1 = ((ii.x + 5) % GX) >> 4;
  int ty0 = ii.y >> 5, ty1 = ((ii.y + 5) % GY) >> 5;
  int p = atomicAdd(&bcur[tx0*NTY+ty0],1); bent[p] = m;
  if (tx1!=tx0){ p = atomicAdd(&bcur[tx1*NTY+ty0],1); bent[p] = m; }
  if (ty1!=ty0){
    p = atomicAdd(&bcur[tx0*NTY+ty1],1); bent[p] = m;
    if (tx1!=tx0){ p = atomicAdd(&bcur[tx1*NTY+ty1],1); bent[p] = m; }
  }
}

// ---------- tile gather: 16x32 tile, 512 threads, 1 cell/thread, packed f32x2 FMA ----------
template<int BC>
__global__ __launch_bounds__(512, 4) void tile_gather(const float* __restrict__ ydc,
                                                      const float* __restrict__ wtab,
                                                      const int2* __restrict__ itab,
                                                      const int* __restrict__ bstart,
                                                      const int* __restrict__ bend,
                                                      const int* __restrict__ bent,
                                                      bf16* __restrict__ A1, int c0){
  int tile = blockIdx.x;
  int tx = tile / NTY, ty = tile - tx*NTY;
  int x0 = tx*16, y0 = ty*32;
  int t = threadIdx.x;
  int kxl = t >> 5;
  int kyl = t & 31;
  int kxi = x0 + kxl;
  int kyi = y0 + kyl;

  __shared__ float swx[CHUNK][6], swy[CHUNK][6];
  __shared__ float sy[CHUNK][2*BC];
  __shared__ int   six0[CHUNK], siy0[CHUNK];

  f32x2 accv[BC];
  #pragma unroll
  for (int c=0;c<BC;++c){ accv[c] = (f32x2){0.f, 0.f}; }

  int beg = bstart[tile], end = bend[tile];
  for (int s0 = beg; s0 < end; s0 += CHUNK){
    int ns = end - s0; if (ns > CHUNK) ns = CHUNK;
    __syncthreads();
    for (int i=t; i<ns; i+=512){
      int m = bent[s0+i];
      const float4* wt = (const float4*)(wtab + (size_t)m*12);
      float4 w0 = wt[0], w1 = wt[1], w2 = wt[2];
      swx[i][0]=w0.x; swx[i][1]=w0.y; swx[i][2]=w0.z; swx[i][3]=w0.w;
      swx[i][4]=w1.x; swx[i][5]=w1.y;
      swy[i][0]=w1.z; swy[i][1]=w1.w; swy[i][2]=w2.x; swy[i][3]=w2.y;
      swy[i][4]=w2.z; swy[i][5]=w2.w;
      int2 ii = itab[m];
      six0[i] = ii.x; siy0[i] = ii.y;
    }
    for (int i=t; i<ns*2*BC; i+=512){
      int s = i / (2*BC), f = i - s*(2*BC);
      sy[s][f] = ydc[((size_t)bent[s0+s]*NC + c0)*2 + f];
    }
    __syncthreads();
    for (int s=0; s<ns; ++s){
      int lx = kxi - six0[s]; if (lx < 0) lx += GX;
      if (lx < 6){
        int ly = kyi - siy0[s]; if (ly < 0) ly += GY;
        float w = (ly < 6) ? swx[s][lx] * swy[s][ly] : 0.0f;
        f32x2 wv = (f32x2){w, w};
        const f32x2* syv = (const f32x2*)&sy[s][0];
        #pragma unroll
        for (int c=0;c<BC;++c){
          accv[c] += wv * syv[c];
        }
      }
    }
  }

  float mask = (kyi < GY) ? 1.0f : 0.0f;
  #pragma unroll
  for (int c=0;c<BC;++c){
    size_t base = ((size_t)((c*GX + kxi)*2)) * K1;
    A1[base + kyi]      = (bf16)(accv[c][0]*mask);
    A1[base + K1 + kyi] = (bf16)(accv[c][1]*mask);
  }
}

// ---------- GEMM1 with in-staging ky-fold, 512 threads / 8 waves (known-good) ----------
#define BM 128
#define BN 128
#define BK 32
#define LDT 40

__device__ __forceinline__ void fold8(bf16x8 own, bf16x8 mA, bf16x8 mB, int k0,
                                      bf16x8& pv, bf16x8& mv){
  float mir[8];
  mir[0]=(float)mB[4]; mir[1]=(float)mB[3]; mir[2]=(float)mB[2]; mir[3]=(float)mB[1];
  mir[4]=(float)mB[0]; mir[5]=(float)mA[7]; mir[6]=(float)mA[6]; mir[7]=(float)mA[5];
  #pragma unroll
  for (int j=0;j<8;++j){
    float mm = (k0 + j == 474) ? 0.f : mir[j];
    float ov = (float)own[j];
    pv[j] = (bf16)(ov + mm);
    mv[j] = (bf16)(ov - mm);
  }
}

__global__ __launch_bounds__(512) void gemm1_fold(const bf16* __restrict__ A,
                                                  const bf16* __restrict__ B,
                                                  bf16* __restrict__ C,
                                                  int ldc){
  int total = gridDim.x;
  int qq = total >> 3, rr = total & 7;
  int d = blockIdx.x;
  int xcd = d & 7, jj = d >> 3;
  int L = (xcd < rr) ? (xcd*(qq+1) + jj) : (rr*(qq+1) + (xcd-rr)*qq + jj);
  size_t tileM = (size_t)(L % 3) * BM;
  size_t tileN = (size_t)(L / 3) * BN;

  __shared__ bf16 As[BM*LDT];
  __shared__ bf16 Bp[BM*LDT];
  __shared__ bf16 Bm[BM*LDT];
  int t = threadIdx.x;
  int lane = t & 63;
  int wave = t >> 6;
  int wm = wave >> 2, wn = wave & 3;
  bool isCos = (tileM + (size_t)wm*64) < 192;

  f32x4 zero = {0.f, 0.f, 0.f, 0.f};
  f32x4 acc[4][2];
  #pragma unroll
  for (int m=0;m<4;++m)
    #pragma unroll
    for (int n=0;n<2;++n) acc[m][n] = zero;

  int r0 = t >> 2;
  int kc = (t & 3) * 8;
  const bf16* Arow = A + (tileM + r0) * (size_t)K1F + kc;
  const bf16* Brow = B + (tileN + r0) * (size_t)K1;

  bf16x8 a0  = *(const bf16x8*)(Arow);
  bf16x8 o0  = *(const bf16x8*)(Brow + kc);
  bf16x8 mA0 = *(const bf16x8*)(Brow + 936 - kc);
  bf16x8 mB0 = *(const bf16x8*)(Brow + 944 - kc);

  int lr = lane & 15, lk = (lane >> 4) * 8;

  for (int kt = 0; kt < K1F; kt += BK){
    bf16x8 p0, m0;
    fold8(o0, mA0, mB0, kt + kc, p0, m0);
    __syncthreads();
    *(bf16x8*)(As + r0*LDT + kc) = a0;
    *(bf16x8*)(Bp + r0*LDT + kc) = p0;
    *(bf16x8*)(Bm + r0*LDT + kc) = m0;
    __syncthreads();

    if (kt + BK < K1F){
      int kn = kt + BK + kc;
      a0  = *(const bf16x8*)(Arow + kt + BK);
      o0  = *(const bf16x8*)(Brow + kn);
      mA0 = *(const bf16x8*)(Brow + 936 - kn);
      mB0 = *(const bf16x8*)(Brow + 944 - kn);
    }

    const bf16* Bsel = isCos ? Bp : Bm;
    bf16x8 af[4], bg[2];
    #pragma unroll
    for (int m=0;m<4;++m)
      af[m] = *(const bf16x8*)(As + (wm*64 + m*16 + lr)*LDT + lk);
    #pragma unroll
    for (int n=0;n<2;++n)
      bg[n] = *(const bf16x8*)(Bsel + (wn*32 + n*16 + lr)*LDT + lk);
    #pragma unroll
    for (int m=0;m<4;++m)
      #pragma unroll
      for (int n=0;n<2;++n)
        acc[m][n] = __builtin_amdgcn_mfma_f32_16x16x32_bf16(af[m], bg[n], acc[m][n], 0, 0, 0);
  }

  int lrow = (lane >> 4) * 4;
  #pragma unroll
  for (int m=0;m<4;++m)
    #pragma unroll
    for (int n=0;n<2;++n){
      size_t row = tileM + wm*64 + m*16 + lrow;
      size_t col = tileN + wn*32 + n*16 + lr;
      #pragma unroll
      for (int r2=0;r2<4;++r2)
        C[(row + r2)*(size_t)ldc + col] = (bf16)acc[m][n][r2];
    }
}

// ---------- pack C1t(bf16) -> folded A2p/A2m (cos row n; sin row 192+n) ----------
__global__ void pack_fold(const bf16* __restrict__ C1t, bf16* __restrict__ A2p,
                          bf16* __restrict__ A2m, int nb, int ldc1){
  int i = blockIdx.x*256 + threadIdx.x;
  if (i >= nb*161*80) return;
  int kxg = i % 80;
  int rem = i / 80;
  int n   = rem % 161;
  int cl  = rem / 161;
  int kx0 = kxg*8;

  const bf16* rowC = C1t + (size_t)n*ldc1;
  const bf16* rowS = C1t + (size_t)(192+n)*ldc1;
  int ob = cl*2560 + kx0*2;
  int mb = 1280 - kx0 - 8;
  int mbb = cl*2560 + mb*2;

  float CRo[8], CIo[8], SRo[8], SIo[8];
  {
    bf16x8 c0 = *(const bf16x8*)(rowC + ob);
    bf16x8 c1 = *(const bf16x8*)(rowC + ob + 8);
    bf16x8 s0 = *(const bf16x8*)(rowS + ob);
    bf16x8 s1 = *(const bf16x8*)(rowS + ob + 8);
    #pragma unroll
    for (int j=0;j<4;++j){
      CRo[j]   = (float)c0[2*j]; CIo[j]   = (float)c0[2*j+1];
      CRo[j+4] = (float)c1[2*j]; CIo[j+4] = (float)c1[2*j+1];
      SRo[j]   = (float)s0[2*j]; SIo[j]   = (float)s0[2*j+1];
      SRo[j+4] = (float)s1[2*j]; SIo[j+4] = (float)s1[2*j+1];
    }
  }
  float CRm[16], CIm[16], SRm[16], SIm[16];
  {
    #pragma unroll
    for (int h=0;h<4;++h){
      bf16x8 cm = *(const bf16x8*)(rowC + mbb + 8*h);
      bf16x8 sm = *(const bf16x8*)(rowS + mbb + 8*h);
      #pragma unroll
      for (int j=0;j<4;++j){
        CRm[h*4+j] = (float)cm[2*j]; CIm[h*4+j] = (float)cm[2*j+1];
        SRm[h*4+j] = (float)sm[2*j]; SIm[h*4+j] = (float)sm[2*j+1];
      }
    }
  }

  #pragma unroll
  for (int br=0; br<2; ++br){
    bool valid = (br==0) ? (n <= 159) : (n >= 1);
    if (!valid) continue;
    int qv = (br==0) ? (160+n) : (160-n);
    bf16x8 pre, mre, pim, mim;
    #pragma unroll
    for (int j=0;j<8;++j){
      float tro, tio, trm, tim_;
      if (br==0){ tro = CRo[j]-SIo[j]; tio = SRo[j]+CIo[j]; }
      else      { tro = CRo[j]+SIo[j]; tio = CIo[j]-SRo[j]; }
      int mi = 8 - j;
      if (br==0){ trm = CRm[mi]-SIm[mi]; tim_ = SRm[mi]+CIm[mi]; }
      else      { trm = CRm[mi]+SIm[mi]; tim_ = CIm[mi]-SRm[mi]; }
      if (j==0 && kxg==0){ trm = 0.f; tim_ = 0.f; }
      pre[j] = (bf16)(tro + trm); mre[j] = (bf16)(tro - trm);
      pim[j] = (bf16)(tio + tim_); mim[j] = (bf16)(tio - tim_);
    }
    size_t r0 = ((size_t)(cl*640 + 2*qv))*K2F;
    *(bf16x8*)(A2p + r0 + kx0)        = pre;
    *(bf16x8*)(A2m + r0 + kx0)        = mre;
    *(bf16x8*)(A2p + r0 + K2F + kx0)  = pim;
    *(bf16x8*)(A2m + r0 + K2F + kx0)  = mim;
    if (kxg == 0){
      bf16x8 c6 = *(const bf16x8*)(rowC + cl*2560 + 1280);
      bf16x8 s6 = *(const bf16x8*)(rowS + cl*2560 + 1280);
      float CR6 = (float)c6[0], CI6 = (float)c6[1];
      float SR6 = (float)s6[0], SI6 = (float)s6[1];
      float t6re, t6im;
      if (br==0){ t6re = CR6-SI6; t6im = SR6+CI6; }
      else      { t6re = CR6+SI6; t6im = CI6-SR6; }
      A2p[r0 + 640]       = (bf16)t6re;
      A2p[r0 + K2F + 640] = (bf16)t6im;
      A2m[r0 + 640]       = (bf16)0.f;
      A2m[r0 + K2F + 640] = (bf16)0.f;
    }
  }
}

// ---------- GEMM2: 64x128 tiles, fp32 C, both folds via blockIdx.z ----------
__global__ __launch_bounds__(256) void gemm2_wide(const bf16* __restrict__ Acos,
                                                  const bf16* __restrict__ Bcos,
                                                  float* __restrict__ Ccos,
                                                  const bf16* __restrict__ Asin,
                                                  const bf16* __restrict__ Bsin,
                                                  float* __restrict__ Csin,
                                                  int K, int ldc){
  const bf16* A = blockIdx.z ? Asin : Acos;
  const bf16* B = blockIdx.z ? Bsin : Bcos;
  float*      C = blockIdx.z ? Csin : Ccos;

  __shared__ bf16 As[64*LDT];
  __shared__ bf16 Bs[128*LDT];
  int t = threadIdx.x;
  int lane = t & 63;
  int wave = t >> 6;
  int wm = wave >> 1, wn = wave & 1;     // wave tile 32M x 64N
  size_t tileM = (size_t)blockIdx.x * 64;
  size_t tileN = (size_t)blockIdx.y * 128;

  const bf16* Ab = A + tileM * K;
  const bf16* Bb = B + tileN * K;

  f32x4 zero = {0.f, 0.f, 0.f, 0.f};
  f32x4 acc[2][4];
  #pragma unroll
  for (int m=0;m<2;++m)
    #pragma unroll
    for (int n=0;n<4;++n) acc[m][n] = zero;

  int r0 = t >> 2;
  int kc = (t & 3) * 8;
  size_t aoff = (size_t)r0 * K + kc;

  bf16x8 a0 = *(const bf16x8*)(Ab + aoff);
  bf16x8 b0 = *(const bf16x8*)(Bb + aoff);
  bf16x8 b1 = *(const bf16x8*)(Bb + aoff + (size_t)64*K);

  int lr = lane & 15, lk = (lane >> 4) * 8;

  for (int kt = 0; kt < K; kt += BK){
    __syncthreads();
    *(bf16x8*)(As + r0*LDT + kc)      = a0;
    *(bf16x8*)(Bs + r0*LDT + kc)      = b0;
    *(bf16x8*)(Bs + (r0+64)*LDT + kc) = b1;
    __syncthreads();

    bool more = (kt + BK) < K;
    if (more){
      size_t o = aoff + kt + BK;
      a0 = *(const bf16x8*)(Ab + o);
      b0 = *(const bf16x8*)(Bb + o);
      b1 = *(const bf16x8*)(Bb + o + (size_t)64*K);
    }

    bf16x8 af[2], bg[4];
    #pragma unroll
    for (int m=0;m<2;++m)
      af[m] = *(const bf16x8*)(As + (wm*32 + m*16 + lr)*LDT + lk);
    #pragma unroll
    for (int n=0;n<4;++n)
      bg[n] = *(const bf16x8*)(Bs + (wn*64 + n*16 + lr)*LDT + lk);
    #pragma unroll
    for (int m=0;m<2;++m)
      #pragma unroll
      for (int n=0;n<4;++n)
        acc[m][n] = __builtin_amdgcn_mfma_f32_16x16x32_bf16(af[m], bg[n], acc[m][n], 0, 0, 0);
  }

  int lrow = (lane >> 4) * 4;
  #pragma unroll
  for (int m=0;m<2;++m)
    #pragma unroll
    for (int n=0;n<4;++n){
      size_t row = tileM + wm*32 + m*16 + lrow;
      size_t col = tileN + wn*64 + n*16 + lr;
      #pragma unroll
      for (int r=0;r<4;++r)
        C[(row + r)*(size_t)ldc + col] = acc[m][n][r];
    }
}

// ---------- deapodization ----------
__device__ __forceinline__ float deapod_f(float n, float G){
  float x = 3.14159265358979323846f * 6.0f * n / G;
  float z = 197.1216f - x*x;
  float sz = sqrtf(fabsf(z) + 1e-12f);
  float K;
  if (z > 0.0f){
    float e = __expf(sz);
    K = (e - 1.0f/e)*0.5f/sz;
  } else {
    K = __sinf(sz)/sz;
  }
  return 1.0f/K;
}

// ---------- fused coil combine + deapod + magnitude (single-batch path) ----------
__global__ void combine_final(const float* __restrict__ Oc, const float* __restrict__ Os,
                              const float* __restrict__ smr, const float* __restrict__ smi,
                              float* __restrict__ out, int bc, int ldo){
  int i = blockIdx.x*256 + threadIdx.x;
  if (i >= CROPN*CROPN) return;
  int r = i / CROPN, q = i - r*CROPN;
  const float* rc = Oc + (size_t)r*ldo;
  const float* rs = Os + (size_t)r*ldo;
  float ar = 0.f, ai = 0.f;
  for (int cl=0; cl<bc; ++cl){
    int cb = cl*640 + 2*q;
    float re = rc[cb]   - rs[cb+1];
    float im = rc[cb+1] + rs[cb];
    size_t sidx = ((size_t)cl*HH + (160+r))*WW + (77+q);
    float sr = smr[sidx], si = smi[sidx];
    ar += sr*re + si*im;
    ai += sr*im - si*re;
  }
  float dx = deapod_f((float)(r - 160), (float)GX);
  float dy = deapod_f((float)(q - 160), (float)GY);
  out[i] = sqrtf(ar*ar + ai*ai) * dx * dy;
}

// ---------- multi-batch fallback ----------
__global__ void combine(const float* __restrict__ Oc, const float* __restrict__ Os,
                        const float* __restrict__ smr, const float* __restrict__ smi,
                        float* __restrict__ accum, int c0, int bc, int ldo){
  int i = blockIdx.x*256 + threadIdx.x;
  if (i >= CROPN*CROPN) return;
  int r = i / CROPN, q = i - r*CROPN;
  const float* rc = Oc + (size_t)r*ldo;
  const float* rs = Os + (size_t)r*ldo;
  float ar = 0.f, ai = 0.f;
  for (int cl=0; cl<bc; ++cl){
    int cb = cl*640 + 2*q;
    float re = rc[cb]   - rs[cb+1];
    float im = rc[cb+1] + rs[cb];
    size_t sidx = ((size_t)(c0+cl)*HH + (160+r))*WW + (77+q);
    float sr = smr[sidx], si = smi[sidx];
    ar += sr*re + si*im;
    ai += sr*im - si*re;
  }
  accum[2*i] += ar; accum[2*i+1] += ai;
}

__global__ void final_mag(const float* __restrict__ accum, float* __restrict__ out){
  int i = blockIdx.x*256 + threadIdx.x;
  if (i >= CROPN*CROPN) return;
  int r  = i / CROPN;
  int cc = i - r*CROPN;
  float dx = deapod_f((float)(r  - 160), (float)GX);
  float dy = deapod_f((float)(cc - 160), (float)GY);
  float re = accum[2*i], im = accum[2*i+1];
  out[i] = sqrtf(re*re + im*im) * dx * dy;
}

// gather dispatch helper
static void launch_gather(int nb, const float* ydc, const float* wtab, const int2* itab,
                          const int* bstart, const int* bcur, const int* bent,
                          bf16* A1, int c0, hipStream_t stream){
  switch (nb){
    case 1:  tile_gather<1><<<NTILE,512,0,stream>>>(ydc,wtab,itab,bstart,bcur,bent,A1,c0); break;
    case 2:  tile_gather<2><<<NTILE,512,0,stream>>>(ydc,wtab,itab,bstart,bcur,bent,A1,c0); break;
    case 3:  tile_gather<3><<<NTILE,512,0,stream>>>(ydc,wtab,itab,bstart,bcur,bent,A1,c0); break;
    case 4:  tile_gather<4><<<NTILE,512,0,stream>>>(ydc,wtab,itab,bstart,bcur,bent,A1,c0); break;
    case 5:  tile_gather<5><<<NTILE,512,0,stream>>>(ydc,wtab,itab,bstart,bcur,bent,A1,c0); break;
    case 6:  tile_gather<6><<<NTILE,512,0,stream>>>(ydc,wtab,itab,bstart,bcur,bent,A1,c0); break;
    case 7:  tile_gather<7><<<NTILE,512,0,stream>>>(ydc,wtab,itab,bstart,bcur,bent,A1,c0); break;
    case 8:  tile_gather<8><<<NTILE,512,0,stream>>>(ydc,wtab,itab,bstart,bcur,bent,A1,c0); break;
    case 9:  tile_gather<9><<<NTILE,512,0,stream>>>(ydc,wtab,itab,bstart,bcur,bent,A1,c0); break;
    case 10: tile_gather<10><<<NTILE,512,0,stream>>>(ydc,wtab,itab,bstart,bcur,bent,A1,c0); break;
    case 11: tile_gather<11><<<NTILE,512,0,stream>>>(ydc,wtab,itab,bstart,bcur,bent,A1,c0); break;
    case 12: tile_gather<12><<<NTILE,512,0,stream>>>(ydc,wtab,itab,bstart,bcur,bent,A1,c0); break;
    case 13: tile_gather<13><<<NTILE,512,0,stream>>>(ydc,wtab,itab,bstart,bcur,bent,A1,c0); break;
    case 14: tile_gather<14><<<NTILE,512,0,stream>>>(ydc,wtab,itab,bstart,bcur,bent,A1,c0); break;
    default: tile_gather<15><<<NTILE,512,0,stream>>>(ydc,wtab,itab,bstart,bcur,bent,A1,c0); break;
  }
}

extern "C" void kernel_launch(void* const* d_in, const int* in_sizes, int n_in,
                              void* d_out, int out_size, void* d_ws, size_t ws_size,
                              hipStream_t stream){
  const float* kr    = (const float*)d_in[0];
  const float* ki    = (const float*)d_in[1];
  const float* ktraj = (const float*)d_in[2];
  const float* dc    = (const float*)d_in[3];
  const float* smr   = (const float*)d_in[4];
  const float* smi   = (const float*)d_in[5];
  float* out = (float*)d_out;

  // ---- workspace carve (bytes) ----
  const size_t acc_b   = (size_t)CROPN*CROPN*2*4;
  const size_t B1_b    = (size_t)M1*K1F*2;
  const size_t W2_b    = (size_t)M2F*K2F*2;
  const size_t ydc_b   = (size_t)MPTS*NC*2*4;
  const size_t wtab_b  = (size_t)MPTS*12*4;
  const size_t itab_b  = (size_t)MPTS*8;
  const size_t bh_b    = 16384;
  const size_t bent_b  = (size_t)MAXENT*4;
  const size_t fixed_b = acc_b+B1_b+2*W2_b+ydc_b+wtab_b+itab_b+3*bh_b+bent_b;

  const size_t A1_pc   = (size_t)GX*2*K1*2;          // 4,915,200 (A2p+A2m alias)
  const size_t C1_pc   = (size_t)GX*2*M1*2;          // 1,966,080 (Oc+Os alias)
  const size_t percoil = A1_pc + C1_pc;

  int bc = 1;
  if (ws_size > fixed_b + percoil){
    size_t b = (ws_size - fixed_b) / percoil;
    bc = (int)(b > NC ? NC : b);
    if (bc < 1) bc = 1;
  }

  char* p = (char*)d_ws;
  float* accum  = (float*)p; p += acc_b;
  bf16*  B1     = (bf16*)p;  p += B1_b;
  bf16*  W2c    = (bf16*)p;  p += W2_b;
  bf16*  W2s    = (bf16*)p;  p += W2_b;
  float* ydc    = (float*)p; p += ydc_b;
  float* wtab   = (float*)p; p += wtab_b;
  int2*  itab   = (int2*)p;  p += itab_b;
  int*   bhist  = (int*)p;   p += bh_b;
  int*   bstart = (int*)p;   p += bh_b;
  int*   bcur   = (int*)p;   p += bh_b;
  int*   bent   = (int*)p;   p += bent_b;
  bf16*  A1     = (bf16*)p;
  bf16*  A2p    = (bf16*)p;                          // aliases A1 (dead after GEMM1)
  bf16*  A2m    = A2p + (size_t)bc*640*K2F;
  p += (size_t)bc*A1_pc;
  bf16*  C1t    = (bf16*)p;
  float* Oc     = (float*)p;                         // aliases C1t (dead after pack)
  float* Os     = Oc + (size_t)bc*M2F*640;
  p += (size_t)bc*C1_pc;

  // ---- one-time builds ----
  hipMemsetAsync(bhist, 0, NTILE*4, stream);
  prep_gen<<<PREP_BLOCKS + GEN_BLOCKS, 256, 0, stream>>>(kr, ki, dc, ktraj, ydc, wtab,
                                                         itab, bhist, B1, W2c, W2s);
  bin_scan<<<1, 256, 0, stream>>>(bhist, bstart, bcur);
  bin_fill<<<(MPTS+255)/256, 256, 0, stream>>>(itab, bcur, bent);
  if (bc < NC) hipMemsetAsync(accum, 0, acc_b, stream);

  // ---- per coil-batch pipeline ----
  for (int c0 = 0; c0 < NC; c0 += bc){
    int nb = NC - c0; if (nb > bc) nb = bc;
    int ncols = nb*2560;

    launch_gather(nb, ydc, wtab, itab, bstart, bcur, bent, A1, c0, stream);

    // GEMM1 with in-staging ky-fold: K=480, 512 threads/8 waves, trio-XCD-swizzled
    gemm1_fold<<<3*(ncols/BN), 512, 0, stream>>>(B1, A1, C1t, ncols);

    int tot2 = nb*161*80;
    pack_fold<<<(tot2+255)/256, 256, 0, stream>>>(C1t, A2p, A2m, nb, ncols);

    // GEMM2 (folded): 64x128 tiles; z=0 Oc = W2c x A2p^T, z=1 Os = W2s x A2m^T
    gemm2_wide<<<dim3(M2F/64, nb*640/128, 2), 256, 0, stream>>>(W2c, A2p, Oc,
                                                                W2s, A2m, Os,
                                                                K2F, nb*640);

    if (bc >= NC){
      combine_final<<<(CROPN*CROPN+255)/256, 256, 0, stream>>>(Oc, Os, smr, smi, out, nb, nb*640);
    } else {
      combine<<<(CROPN*CROPN+255)/256, 256, 0, stream>>>(Oc, Os, smr, smi, accum, c0, nb, nb*640);
    }
  }
  if (bc < NC)
    final_mag<<<(CROPN*CROPN+255)/256, 256, 0, stream>>>(accum, out);
}

// Round 20
// 153.033 us; speedup vs baseline: 1.0937x; 1.0005x over previous
//
#include <hip/hip_runtime.h>

typedef __bf16 bf16;
typedef __attribute__((ext_vector_type(8))) __bf16 bf16x8;
typedef __attribute__((ext_vector_type(4))) float f32x4;
typedef __attribute__((ext_vector_type(2))) float f32x2;

#define MPTS 40960
#define NC 15
#define GX 1280
#define GY 948
#define HH 640
#define WW 474
#define CROPN 320

#define K1 960    // A1 row width (ky padded 948->960)
#define K1F 480   // folded ky K for GEMM1
#define M1 384    // rows: [0,192)=cos n, [192,384)=sin n
#define K2F 672   // folded kx
#define M2F 320

#define NTX 80
#define NTY 30
#define NTILE (NTX*NTY)   // 2400
#define MAXENT (MPTS*4)
#define CHUNK 128

// ---------- modified Bessel I0 ----------
__device__ __forceinline__ float i0f_dev(float x){
  if (x < 3.75f){
    float t = x*(1.0f/3.75f); t *= t;
    return 1.0f + t*(3.5156229f + t*(3.0899424f + t*(1.2067492f +
                 t*(0.2659732f + t*(0.0360768f + t*0.0045813f)))));
  } else {
    float t = 3.75f/x;
    float p = 0.39894228f + t*(0.01328592f + t*(0.00225319f + t*(-0.00157565f +
              t*(0.00916281f + t*(-0.02057706f + t*(0.02635537f +
              t*(-0.01647633f + t*0.00392377f)))))));
    return __expf(x)*rsqrtf(x)*p;
  }
}

__device__ __forceinline__ float kb_w(float u){
  float a = 1.0f - u*u*(1.0f/9.0f);
  return i0f_dev(14.04f*sqrtf(fmaxf(a, 0.0f)))*(1.0f/6.0f);
}

#define B1_ELEMS (M1*K1F)
#define W2_ELEMS (M2F*K2F)
#define PREP_BLOCKS ((MPTS+255)/256)
#define GEN_BLOCKS  ((B1_ELEMS+W2_ELEMS+255)/256)

// ---------- fused prep (ydc/wtab/itab/hist) + twiddle gen ----------
__global__ void prep_gen(const float* __restrict__ kr, const float* __restrict__ ki,
                         const float* __restrict__ dc, const float* __restrict__ ktraj,
                         float* __restrict__ ydc, float* __restrict__ wtab,
                         int2* __restrict__ itab, int* __restrict__ bhist,
                         bf16* __restrict__ B1, bf16* __restrict__ W2c,
                         bf16* __restrict__ W2s){
  int b = blockIdx.x;
  if (b < PREP_BLOCKS){
    int m = b*256 + threadIdx.x;
    if (m >= MPTS) return;
    float d = dc[m];
    #pragma unroll
    for (int c=0;c<NC;++c){
      ydc[((size_t)m*NC + c)*2    ] = kr[(size_t)c*MPTS + m]*d;
      ydc[((size_t)m*NC + c)*2 + 1] = ki[(size_t)c*MPTS + m]*d;
    }
    const float PI2 = 6.28318530717958647692f;
    float tmx = ktraj[m]        * ((float)GX/PI2);
    float tmy = ktraj[MPTS + m] * ((float)GY/PI2);
    float bx = floorf(tmx - 3.0f), by = floorf(tmy - 3.0f);
    float wx[6], wy[6];
    #pragma unroll
    for (int j=0;j<6;++j){
      wx[j] = kb_w(tmx - (bx + (float)(j+1)));
      wy[j] = kb_w(tmy - (by + (float)(j+1)));
    }
    float4* wt = (float4*)(wtab + (size_t)m*12);
    wt[0] = make_float4(wx[0], wx[1], wx[2], wx[3]);
    wt[1] = make_float4(wx[4], wx[5], wy[0], wy[1]);
    wt[2] = make_float4(wy[2], wy[3], wy[4], wy[5]);
    int ix0 = ((int)bx + 1) % GX; if (ix0 < 0) ix0 += GX;
    int iy0 = ((int)by + 1) % GY; if (iy0 < 0) iy0 += GY;
    itab[m] = make_int2(ix0, iy0);
    int tx0 = ix0 >> 4, tx1 = ((ix0 + 5) % GX) >> 4;
    int ty0 = iy0 >> 5, ty1 = ((iy0 + 5) % GY) >> 5;
    atomicAdd(&bhist[tx0*NTY+ty0],1);
    if (tx1!=tx0) atomicAdd(&bhist[tx1*NTY+ty0],1);
    if (ty1!=ty0){
      atomicAdd(&bhist[tx0*NTY+ty1],1);
      if (tx1!=tx0) atomicAdd(&bhist[tx1*NTY+ty1],1);
    }
    return;
  }
  int i = (b - PREP_BLOCKS)*256 + threadIdx.x;
  if (i < B1_ELEMS){
    int r = i / K1F, k = i - r*K1F;
    float v = 0.f;
    if (k <= 474){
      if (r < 192){
        int n = r;
        if (n <= 160){
          int rem = (k * n) % GY;
          float ang = 6.28318530717958647692f * (float)rem / (float)GY;
          float s, c; sincosf(ang, &s, &c); v = c;
        }
      } else {
        int n = r - 192;
        if (n >= 1 && n <= 160){
          int rem = (k * n) % GY;
          float ang = 6.28318530717958647692f * (float)rem / (float)GY;
          float s, c; sincosf(ang, &s, &c); v = s;
        }
      }
    }
    B1[i] = (bf16)v;
  } else if (i < B1_ELEMS + W2_ELEMS){
    int j = i - B1_ELEMS;
    int r = j / K2F, k = j - r*K2F;
    int nx = (r < 160) ? (1120 + r) : (r - 160);
    float vc = 0.f, vs = 0.f;
    if (k < 640){
      int rem = (k * nx) % GX;
      float ang = 6.28318530717958647692f * (float)rem / (float)GX;
      float s, c; sincosf(ang, &s, &c);
      vc = c; vs = s;
    } else if (k == 640){
      vc = (nx & 1) ? -1.f : 1.f; vs = 0.f;
    }
    W2c[j] = (bf16)vc;
    W2s[j] = (bf16)vs;
  }
}

#define SCAN_PER 10
__global__ __launch_bounds__(256) void bin_scan(const int* __restrict__ bhist,
                                                int* __restrict__ bstart,
                                                int* __restrict__ bcur){
  __shared__ int ps[256];
  int t = threadIdx.x;
  int v[SCAN_PER]; int s = 0;
  #pragma unroll
  for (int j=0;j<SCAN_PER;++j){ int i = t*SCAN_PER+j; v[j] = (i<NTILE)?bhist[i]:0; s += v[j]; }
  ps[t] = s; __syncthreads();
  for (int off=1; off<256; off<<=1){
    int x = (t>=off) ? ps[t-off] : 0;
    __syncthreads();
    ps[t] += x;
    __syncthreads();
  }
  int run = (t==0) ? 0 : ps[t-1];
  #pragma unroll
  for (int j=0;j<SCAN_PER;++j){
    int i = t*SCAN_PER+j;
    if (i<NTILE){ bstart[i]=run; bcur[i]=run; }
    run += v[j];
  }
}

__global__ void bin_fill(const int2* __restrict__ itab, int* __restrict__ bcur,
                         int* __restrict__ bent){
  int m = blockIdx.x*256 + threadIdx.x;
  if (m >= MPTS) return;
  int2 ii = itab[m];
  int tx0 = ii.x >> 4, tx1 = ((ii.x + 5) % GX) >> 4;
  int ty0 = ii.y >> 5, ty1 = ((ii.y + 5) % GY) >> 5;
  int p = atomicAdd(&bcur[tx0*NTY+ty0],1); bent[p] = m;
  if (tx1!=tx0){ p = atomicAdd(&bcur[tx1*NTY+ty0],1); bent[p] = m; }
  if (ty1!=ty0){
    p = atomicAdd(&bcur[tx0*NTY+ty1],1); bent[p] = m;
    if (tx1!=tx0){ p = atomicAdd(&bcur[tx1*NTY+ty1],1); bent[p] = m; }
  }
}

// ---------- tile gather: 16x32 tile, 512 threads, 1 cell/thread, packed f32x2 FMA ----------
template<int BC>
__global__ __launch_bounds__(512, 4) void tile_gather(const float* __restrict__ ydc,
                                                      const float* __restrict__ wtab,
                                                      const int2* __restrict__ itab,
                                                      const int* __restrict__ bstart,
                                                      const int* __restrict__ bend,
                                                      const int* __restrict__ bent,
                                                      bf16* __restrict__ A1, int c0){
  int tile = blockIdx.x;
  int tx = tile / NTY, ty = tile - tx*NTY;
  int x0 = tx*16, y0 = ty*32;
  int t = threadIdx.x;
  int kxl = t >> 5;
  int kyl = t & 31;
  int kxi = x0 + kxl;
  int kyi = y0 + kyl;

  __shared__ float swx[CHUNK][6], swy[CHUNK][6];
  __shared__ float sy[CHUNK][2*BC];
  __shared__ int   six0[CHUNK], siy0[CHUNK];

  f32x2 accv[BC];
  #pragma unroll
  for (int c=0;c<BC;++c){ accv[c] = (f32x2){0.f, 0.f}; }

  int beg = bstart[tile], end = bend[tile];
  for (int s0 = beg; s0 < end; s0 += CHUNK){
    int ns = end - s0; if (ns > CHUNK) ns = CHUNK;
    __syncthreads();
    for (int i=t; i<ns; i+=512){
      int m = bent[s0+i];
      const float4* wt = (const float4*)(wtab + (size_t)m*12);
      float4 w0 = wt[0], w1 = wt[1], w2 = wt[2];
      swx[i][0]=w0.x; swx[i][1]=w0.y; swx[i][2]=w0.z; swx[i][3]=w0.w;
      swx[i][4]=w1.x; swx[i][5]=w1.y;
      swy[i][0]=w1.z; swy[i][1]=w1.w; swy[i][2]=w2.x; swy[i][3]=w2.y;
      swy[i][4]=w2.z; swy[i][5]=w2.w;
      int2 ii = itab[m];
      six0[i] = ii.x; siy0[i] = ii.y;
    }
    for (int i=t; i<ns*2*BC; i+=512){
      int s = i / (2*BC), f = i - s*(2*BC);
      sy[s][f] = ydc[((size_t)bent[s0+s]*NC + c0)*2 + f];
    }
    __syncthreads();
    for (int s=0; s<ns; ++s){
      int lx = kxi - six0[s]; if (lx < 0) lx += GX;
      if (lx < 6){
        int ly = kyi - siy0[s]; if (ly < 0) ly += GY;
        float w = (ly < 6) ? swx[s][lx] * swy[s][ly] : 0.0f;
        f32x2 wv = (f32x2){w, w};
        const f32x2* syv = (const f32x2*)&sy[s][0];
        #pragma unroll
        for (int c=0;c<BC;++c){
          accv[c] += wv * syv[c];
        }
      }
    }
  }

  float mask = (kyi < GY) ? 1.0f : 0.0f;
  #pragma unroll
  for (int c=0;c<BC;++c){
    size_t base = ((size_t)((c*GX + kxi)*2)) * K1;
    A1[base + kyi]      = (bf16)(accv[c][0]*mask);
    A1[base + K1 + kyi] = (bf16)(accv[c][1]*mask);
  }
}

// ---------- GEMM1 with in-staging ky-fold + 2-deep register prefetch ----------
#define BM 128
#define BN 128
#define BK 32
#define LDT 40

__device__ __forceinline__ void fold8(bf16x8 own, bf16x8 mA, bf16x8 mB, int k0,
                                      bf16x8& pv, bf16x8& mv){
  float mir[8];
  mir[0]=(float)mB[4]; mir[1]=(float)mB[3]; mir[2]=(float)mB[2]; mir[3]=(float)mB[1];
  mir[4]=(float)mB[0]; mir[5]=(float)mA[7]; mir[6]=(float)mA[6]; mir[7]=(float)mA[5];
  #pragma unroll
  for (int j=0;j<8;++j){
    float mm = (k0 + j == 474) ? 0.f : mir[j];
    float ov = (float)own[j];
    pv[j] = (bf16)(ov + mm);
    mv[j] = (bf16)(ov - mm);
  }
}

__global__ __launch_bounds__(512) void gemm1_fold(const bf16* __restrict__ A,
                                                  const bf16* __restrict__ B,
                                                  bf16* __restrict__ C,
                                                  int ldc){
  int total = gridDim.x;
  int qq = total >> 3, rr = total & 7;
  int d = blockIdx.x;
  int xcd = d & 7, jj = d >> 3;
  int L = (xcd < rr) ? (xcd*(qq+1) + jj) : (rr*(qq+1) + (xcd-rr)*qq + jj);
  size_t tileM = (size_t)(L % 3) * BM;
  size_t tileN = (size_t)(L / 3) * BN;

  __shared__ bf16 As[BM*LDT];
  __shared__ bf16 Bp[BM*LDT];
  __shared__ bf16 Bm[BM*LDT];
  int t = threadIdx.x;
  int lane = t & 63;
  int wave = t >> 6;
  int wm = wave >> 2, wn = wave & 3;
  bool isCos = (tileM + (size_t)wm*64) < 192;

  f32x4 zero = {0.f, 0.f, 0.f, 0.f};
  f32x4 acc[4][2];
  #pragma unroll
  for (int m=0;m<4;++m)
    #pragma unroll
    for (int n=0;n<2;++n) acc[m][n] = zero;

  int r0 = t >> 2;
  int kc = (t & 3) * 8;
  const bf16* Arow = A + (tileM + r0) * (size_t)K1F + kc;
  const bf16* Brow = B + (tileN + r0) * (size_t)K1;

  // 2-deep register prefetch: slot0 holds k = kt, slot1 holds k = kt+32
  bf16x8 a0  = *(const bf16x8*)(Arow);
  bf16x8 o0  = *(const bf16x8*)(Brow + kc);
  bf16x8 mA0 = *(const bf16x8*)(Brow + 936 - kc);
  bf16x8 mB0 = *(const bf16x8*)(Brow + 944 - kc);
  bf16x8 a1  = *(const bf16x8*)(Arow + 32);
  bf16x8 o1  = *(const bf16x8*)(Brow + 32 + kc);
  bf16x8 mA1 = *(const bf16x8*)(Brow + 936 - (32 + kc));
  bf16x8 mB1 = *(const bf16x8*)(Brow + 944 - (32 + kc));

  int lr = lane & 15, lk = (lane >> 4) * 8;

  for (int kt = 0; kt < K1F; kt += 64){
    // ---- body A: consume slot0 (k = kt), prefetch k = kt+64 into slot0 ----
    {
      bf16x8 p0, m0;
      fold8(o0, mA0, mB0, kt + kc, p0, m0);
      __syncthreads();
      *(bf16x8*)(As + r0*LDT + kc) = a0;
      *(bf16x8*)(Bp + r0*LDT + kc) = p0;
      *(bf16x8*)(Bm + r0*LDT + kc) = m0;
      __syncthreads();

      if (kt + 64 < K1F){
        int kn = kt + 64 + kc;
        a0  = *(const bf16x8*)(Arow + kt + 64);
        o0  = *(const bf16x8*)(Brow + kn);
        mA0 = *(const bf16x8*)(Brow + 936 - kn);
        mB0 = *(const bf16x8*)(Brow + 944 - kn);
      }

      const bf16* Bsel = isCos ? Bp : Bm;
      bf16x8 af[4], bg[2];
      #pragma unroll
      for (int m=0;m<4;++m)
        af[m] = *(const bf16x8*)(As + (wm*64 + m*16 + lr)*LDT + lk);
      #pragma unroll
      for (int n=0;n<2;++n)
        bg[n] = *(const bf16x8*)(Bsel + (wn*32 + n*16 + lr)*LDT + lk);
      #pragma unroll
      for (int m=0;m<4;++m)
        #pragma unroll
        for (int n=0;n<2;++n)
          acc[m][n] = __builtin_amdgcn_mfma_f32_16x16x32_bf16(af[m], bg[n], acc[m][n], 0, 0, 0);
    }
    // ---- body B: consume slot1 (k = kt+32), prefetch k = kt+96 into slot1 ----
    if (kt + 32 < K1F){
      bf16x8 p1, m1;
      fold8(o1, mA1, mB1, kt + 32 + kc, p1, m1);
      __syncthreads();
      *(bf16x8*)(As + r0*LDT + kc) = a1;
      *(bf16x8*)(Bp + r0*LDT + kc) = p1;
      *(bf16x8*)(Bm + r0*LDT + kc) = m1;
      __syncthreads();

      if (kt + 96 < K1F){
        int kn = kt + 96 + kc;
        a1  = *(const bf16x8*)(Arow + kt + 96);
        o1  = *(const bf16x8*)(Brow + kn);
        mA1 = *(const bf16x8*)(Brow + 936 - kn);
        mB1 = *(const bf16x8*)(Brow + 944 - kn);
      }

      const bf16* Bsel = isCos ? Bp : Bm;
      bf16x8 af[4], bg[2];
      #pragma unroll
      for (int m=0;m<4;++m)
        af[m] = *(const bf16x8*)(As + (wm*64 + m*16 + lr)*LDT + lk);
      #pragma unroll
      for (int n=0;n<2;++n)
        bg[n] = *(const bf16x8*)(Bsel + (wn*32 + n*16 + lr)*LDT + lk);
      #pragma unroll
      for (int m=0;m<4;++m)
        #pragma unroll
        for (int n=0;n<2;++n)
          acc[m][n] = __builtin_amdgcn_mfma_f32_16x16x32_bf16(af[m], bg[n], acc[m][n], 0, 0, 0);
    }
  }

  int lrow = (lane >> 4) * 4;
  #pragma unroll
  for (int m=0;m<4;++m)
    #pragma unroll
    for (int n=0;n<2;++n){
      size_t row = tileM + wm*64 + m*16 + lrow;
      size_t col = tileN + wn*32 + n*16 + lr;
      #pragma unroll
      for (int r2=0;r2<4;++r2)
        C[(row + r2)*(size_t)ldc + col] = (bf16)acc[m][n][r2];
    }
}

// ---------- pack C1t(bf16) -> folded A2p/A2m (cos row n; sin row 192+n) ----------
__global__ void pack_fold(const bf16* __restrict__ C1t, bf16* __restrict__ A2p,
                          bf16* __restrict__ A2m, int nb, int ldc1){
  int i = blockIdx.x*256 + threadIdx.x;
  if (i >= nb*161*80) return;
  int kxg = i % 80;
  int rem = i / 80;
  int n   = rem % 161;
  int cl  = rem / 161;
  int kx0 = kxg*8;

  const bf16* rowC = C1t + (size_t)n*ldc1;
  const bf16* rowS = C1t + (size_t)(192+n)*ldc1;
  int ob = cl*2560 + kx0*2;
  int mb = 1280 - kx0 - 8;
  int mbb = cl*2560 + mb*2;

  float CRo[8], CIo[8], SRo[8], SIo[8];
  {
    bf16x8 c0 = *(const bf16x8*)(rowC + ob);
    bf16x8 c1 = *(const bf16x8*)(rowC + ob + 8);
    bf16x8 s0 = *(const bf16x8*)(rowS + ob);
    bf16x8 s1 = *(const bf16x8*)(rowS + ob + 8);
    #pragma unroll
    for (int j=0;j<4;++j){
      CRo[j]   = (float)c0[2*j]; CIo[j]   = (float)c0[2*j+1];
      CRo[j+4] = (float)c1[2*j]; CIo[j+4] = (float)c1[2*j+1];
      SRo[j]   = (float)s0[2*j]; SIo[j]   = (float)s0[2*j+1];
      SRo[j+4] = (float)s1[2*j]; SIo[j+4] = (float)s1[2*j+1];
    }
  }
  float CRm[16], CIm[16], SRm[16], SIm[16];
  {
    #pragma unroll
    for (int h=0;h<4;++h){
      bf16x8 cm = *(const bf16x8*)(rowC + mbb + 8*h);
      bf16x8 sm = *(const bf16x8*)(rowS + mbb + 8*h);
      #pragma unroll
      for (int j=0;j<4;++j){
        CRm[h*4+j] = (float)cm[2*j]; CIm[h*4+j] = (float)cm[2*j+1];
        SRm[h*4+j] = (float)sm[2*j]; SIm[h*4+j] = (float)sm[2*j+1];
      }
    }
  }

  #pragma unroll
  for (int br=0; br<2; ++br){
    bool valid = (br==0) ? (n <= 159) : (n >= 1);
    if (!valid) continue;
    int qv = (br==0) ? (160+n) : (160-n);
    bf16x8 pre, mre, pim, mim;
    #pragma unroll
    for (int j=0;j<8;++j){
      float tro, tio, trm, tim_;
      if (br==0){ tro = CRo[j]-SIo[j]; tio = SRo[j]+CIo[j]; }
      else      { tro = CRo[j]+SIo[j]; tio = CIo[j]-SRo[j]; }
      int mi = 8 - j;
      if (br==0){ trm = CRm[mi]-SIm[mi]; tim_ = SRm[mi]+CIm[mi]; }
      else      { trm = CRm[mi]+SIm[mi]; tim_ = CIm[mi]-SRm[mi]; }
      if (j==0 && kxg==0){ trm = 0.f; tim_ = 0.f; }
      pre[j] = (bf16)(tro + trm); mre[j] = (bf16)(tro - trm);
      pim[j] = (bf16)(tio + tim_); mim[j] = (bf16)(tio - tim_);
    }
    size_t r0 = ((size_t)(cl*640 + 2*qv))*K2F;
    *(bf16x8*)(A2p + r0 + kx0)        = pre;
    *(bf16x8*)(A2m + r0 + kx0)        = mre;
    *(bf16x8*)(A2p + r0 + K2F + kx0)  = pim;
    *(bf16x8*)(A2m + r0 + K2F + kx0)  = mim;
    if (kxg == 0){
      bf16x8 c6 = *(const bf16x8*)(rowC + cl*2560 + 1280);
      bf16x8 s6 = *(const bf16x8*)(rowS + cl*2560 + 1280);
      float CR6 = (float)c6[0], CI6 = (float)c6[1];
      float SR6 = (float)s6[0], SI6 = (float)s6[1];
      float t6re, t6im;
      if (br==0){ t6re = CR6-SI6; t6im = SR6+CI6; }
      else      { t6re = CR6+SI6; t6im = CI6-SR6; }
      A2p[r0 + 640]       = (bf16)t6re;
      A2p[r0 + K2F + 640] = (bf16)t6im;
      A2m[r0 + 640]       = (bf16)0.f;
      A2m[r0 + K2F + 640] = (bf16)0.f;
    }
  }
}

// ---------- GEMM2: 64x128 tiles, fp32 C, both folds via blockIdx.z ----------
__global__ __launch_bounds__(256) void gemm2_wide(const bf16* __restrict__ Acos,
                                                  const bf16* __restrict__ Bcos,
                                                  float* __restrict__ Ccos,
                                                  const bf16* __restrict__ Asin,
                                                  const bf16* __restrict__ Bsin,
                                                  float* __restrict__ Csin,
                                                  int K, int ldc){
  const bf16* A = blockIdx.z ? Asin : Acos;
  const bf16* B = blockIdx.z ? Bsin : Bcos;
  float*      C = blockIdx.z ? Csin : Ccos;

  __shared__ bf16 As[64*LDT];
  __shared__ bf16 Bs[128*LDT];
  int t = threadIdx.x;
  int lane = t & 63;
  int wave = t >> 6;
  int wm = wave >> 1, wn = wave & 1;     // wave tile 32M x 64N
  size_t tileM = (size_t)blockIdx.x * 64;
  size_t tileN = (size_t)blockIdx.y * 128;

  const bf16* Ab = A + tileM * K;
  const bf16* Bb = B + tileN * K;

  f32x4 zero = {0.f, 0.f, 0.f, 0.f};
  f32x4 acc[2][4];
  #pragma unroll
  for (int m=0;m<2;++m)
    #pragma unroll
    for (int n=0;n<4;++n) acc[m][n] = zero;

  int r0 = t >> 2;
  int kc = (t & 3) * 8;
  size_t aoff = (size_t)r0 * K + kc;

  bf16x8 a0 = *(const bf16x8*)(Ab + aoff);
  bf16x8 b0 = *(const bf16x8*)(Bb + aoff);
  bf16x8 b1 = *(const bf16x8*)(Bb + aoff + (size_t)64*K);

  int lr = lane & 15, lk = (lane >> 4) * 8;

  for (int kt = 0; kt < K; kt += BK){
    __syncthreads();
    *(bf16x8*)(As + r0*LDT + kc)      = a0;
    *(bf16x8*)(Bs + r0*LDT + kc)      = b0;
    *(bf16x8*)(Bs + (r0+64)*LDT + kc) = b1;
    __syncthreads();

    bool more = (kt + BK) < K;
    if (more){
      size_t o = aoff + kt + BK;
      a0 = *(const bf16x8*)(Ab + o);
      b0 = *(const bf16x8*)(Bb + o);
      b1 = *(const bf16x8*)(Bb + o + (size_t)64*K);
    }

    bf16x8 af[2], bg[4];
    #pragma unroll
    for (int m=0;m<2;++m)
      af[m] = *(const bf16x8*)(As + (wm*32 + m*16 + lr)*LDT + lk);
    #pragma unroll
    for (int n=0;n<4;++n)
      bg[n] = *(const bf16x8*)(Bs + (wn*64 + n*16 + lr)*LDT + lk);
    #pragma unroll
    for (int m=0;m<2;++m)
      #pragma unroll
      for (int n=0;n<4;++n)
        acc[m][n] = __builtin_amdgcn_mfma_f32_16x16x32_bf16(af[m], bg[n], acc[m][n], 0, 0, 0);
  }

  int lrow = (lane >> 4) * 4;
  #pragma unroll
  for (int m=0;m<2;++m)
    #pragma unroll
    for (int n=0;n<4;++n){
      size_t row = tileM + wm*32 + m*16 + lrow;
      size_t col = tileN + wn*64 + n*16 + lr;
      #pragma unroll
      for (int r=0;r<4;++r)
        C[(row + r)*(size_t)ldc + col] = acc[m][n][r];
    }
}

// ---------- deapodization ----------
__device__ __forceinline__ float deapod_f(float n, float G){
  float x = 3.14159265358979323846f * 6.0f * n / G;
  float z = 197.1216f - x*x;
  float sz = sqrtf(fabsf(z) + 1e-12f);
  float K;
  if (z > 0.0f){
    float e = __expf(sz);
    K = (e - 1.0f/e)*0.5f/sz;
  } else {
    K = __sinf(sz)/sz;
  }
  return 1.0f/K;
}

// ---------- fused coil combine + deapod + magnitude (single-batch path) ----------
__global__ void combine_final(const float* __restrict__ Oc, const float* __restrict__ Os,
                              const float* __restrict__ smr, const float* __restrict__ smi,
                              float* __restrict__ out, int bc, int ldo){
  int i = blockIdx.x*256 + threadIdx.x;
  if (i >= CROPN*CROPN) return;
  int r = i / CROPN, q = i - r*CROPN;
  const float* rc = Oc + (size_t)r*ldo;
  const float* rs = Os + (size_t)r*ldo;
  float ar = 0.f, ai = 0.f;
  for (int cl=0; cl<bc; ++cl){
    int cb = cl*640 + 2*q;
    float re = rc[cb]   - rs[cb+1];
    float im = rc[cb+1] + rs[cb];
    size_t sidx = ((size_t)cl*HH + (160+r))*WW + (77+q);
    float sr = smr[sidx], si = smi[sidx];
    ar += sr*re + si*im;
    ai += sr*im - si*re;
  }
  float dx = deapod_f((float)(r - 160), (float)GX);
  float dy = deapod_f((float)(q - 160), (float)GY);
  out[i] = sqrtf(ar*ar + ai*ai) * dx * dy;
}

// ---------- multi-batch fallback ----------
__global__ void combine(const float* __restrict__ Oc, const float* __restrict__ Os,
                        const float* __restrict__ smr, const float* __restrict__ smi,
                        float* __restrict__ accum, int c0, int bc, int ldo){
  int i = blockIdx.x*256 + threadIdx.x;
  if (i >= CROPN*CROPN) return;
  int r = i / CROPN, q = i - r*CROPN;
  const float* rc = Oc + (size_t)r*ldo;
  const float* rs = Os + (size_t)r*ldo;
  float ar = 0.f, ai = 0.f;
  for (int cl=0; cl<bc; ++cl){
    int cb = cl*640 + 2*q;
    float re = rc[cb]   - rs[cb+1];
    float im = rc[cb+1] + rs[cb];
    size_t sidx = ((size_t)(c0+cl)*HH + (160+r))*WW + (77+q);
    float sr = smr[sidx], si = smi[sidx];
    ar += sr*re + si*im;
    ai += sr*im - si*re;
  }
  accum[2*i] += ar; accum[2*i+1] += ai;
}

__global__ void final_mag(const float* __restrict__ accum, float* __restrict__ out){
  int i = blockIdx.x*256 + threadIdx.x;
  if (i >= CROPN*CROPN) return;
  int r  = i / CROPN;
  int cc = i - r*CROPN;
  float dx = deapod_f((float)(r  - 160), (float)GX);
  float dy = deapod_f((float)(cc - 160), (float)GY);
  float re = accum[2*i], im = accum[2*i+1];
  out[i] = sqrtf(re*re + im*im) * dx * dy;
}

// gather dispatch helper
static void launch_gather(int nb, const float* ydc, const float* wtab, const int2* itab,
                          const int* bstart, const int* bcur, const int* bent,
                          bf16* A1, int c0, hipStream_t stream){
  switch (nb){
    case 1:  tile_gather<1><<<NTILE,512,0,stream>>>(ydc,wtab,itab,bstart,bcur,bent,A1,c0); break;
    case 2:  tile_gather<2><<<NTILE,512,0,stream>>>(ydc,wtab,itab,bstart,bcur,bent,A1,c0); break;
    case 3:  tile_gather<3><<<NTILE,512,0,stream>>>(ydc,wtab,itab,bstart,bcur,bent,A1,c0); break;
    case 4:  tile_gather<4><<<NTILE,512,0,stream>>>(ydc,wtab,itab,bstart,bcur,bent,A1,c0); break;
    case 5:  tile_gather<5><<<NTILE,512,0,stream>>>(ydc,wtab,itab,bstart,bcur,bent,A1,c0); break;
    case 6:  tile_gather<6><<<NTILE,512,0,stream>>>(ydc,wtab,itab,bstart,bcur,bent,A1,c0); break;
    case 7:  tile_gather<7><<<NTILE,512,0,stream>>>(ydc,wtab,itab,bstart,bcur,bent,A1,c0); break;
    case 8:  tile_gather<8><<<NTILE,512,0,stream>>>(ydc,wtab,itab,bstart,bcur,bent,A1,c0); break;
    case 9:  tile_gather<9><<<NTILE,512,0,stream>>>(ydc,wtab,itab,bstart,bcur,bent,A1,c0); break;
    case 10: tile_gather<10><<<NTILE,512,0,stream>>>(ydc,wtab,itab,bstart,bcur,bent,A1,c0); break;
    case 11: tile_gather<11><<<NTILE,512,0,stream>>>(ydc,wtab,itab,bstart,bcur,bent,A1,c0); break;
    case 12: tile_gather<12><<<NTILE,512,0,stream>>>(ydc,wtab,itab,bstart,bcur,bent,A1,c0); break;
    case 13: tile_gather<13><<<NTILE,512,0,stream>>>(ydc,wtab,itab,bstart,bcur,bent,A1,c0); break;
    case 14: tile_gather<14><<<NTILE,512,0,stream>>>(ydc,wtab,itab,bstart,bcur,bent,A1,c0); break;
    default: tile_gather<15><<<NTILE,512,0,stream>>>(ydc,wtab,itab,bstart,bcur,bent,A1,c0); break;
  }
}

extern "C" void kernel_launch(void* const* d_in, const int* in_sizes, int n_in,
                              void* d_out, int out_size, void* d_ws, size_t ws_size,
                              hipStream_t stream){
  const float* kr    = (const float*)d_in[0];
  const float* ki    = (const float*)d_in[1];
  const float* ktraj = (const float*)d_in[2];
  const float* dc    = (const float*)d_in[3];
  const float* smr   = (const float*)d_in[4];
  const float* smi   = (const float*)d_in[5];
  float* out = (float*)d_out;

  // ---- workspace carve (bytes) ----
  const size_t acc_b   = (size_t)CROPN*CROPN*2*4;
  const size_t B1_b    = (size_t)M1*K1F*2;
  const size_t W2_b    = (size_t)M2F*K2F*2;
  const size_t ydc_b   = (size_t)MPTS*NC*2*4;
  const size_t wtab_b  = (size_t)MPTS*12*4;
  const size_t itab_b  = (size_t)MPTS*8;
  const size_t bh_b    = 16384;
  const size_t bent_b  = (size_t)MAXENT*4;
  const size_t fixed_b = acc_b+B1_b+2*W2_b+ydc_b+wtab_b+itab_b+3*bh_b+bent_b;

  const size_t A1_pc   = (size_t)GX*2*K1*2;          // 4,915,200 (A2p+A2m alias)
  const size_t C1_pc   = (size_t)GX*2*M1*2;          // 1,966,080 (Oc+Os alias)
  const size_t percoil = A1_pc + C1_pc;

  int bc = 1;
  if (ws_size > fixed_b + percoil){
    size_t b = (ws_size - fixed_b) / percoil;
    bc = (int)(b > NC ? NC : b);
    if (bc < 1) bc = 1;
  }

  char* p = (char*)d_ws;
  float* accum  = (float*)p; p += acc_b;
  bf16*  B1     = (bf16*)p;  p += B1_b;
  bf16*  W2c    = (bf16*)p;  p += W2_b;
  bf16*  W2s    = (bf16*)p;  p += W2_b;
  float* ydc    = (float*)p; p += ydc_b;
  float* wtab   = (float*)p; p += wtab_b;
  int2*  itab   = (int2*)p;  p += itab_b;
  int*   bhist  = (int*)p;   p += bh_b;
  int*   bstart = (int*)p;   p += bh_b;
  int*   bcur   = (int*)p;   p += bh_b;
  int*   bent   = (int*)p;   p += bent_b;
  bf16*  A1     = (bf16*)p;
  bf16*  A2p    = (bf16*)p;                          // aliases A1 (dead after GEMM1)
  bf16*  A2m    = A2p + (size_t)bc*640*K2F;
  p += (size_t)bc*A1_pc;
  bf16*  C1t    = (bf16*)p;
  float* Oc     = (float*)p;                         // aliases C1t (dead after pack)
  float* Os     = Oc + (size_t)bc*M2F*640;
  p += (size_t)bc*C1_pc;

  // ---- one-time builds ----
  hipMemsetAsync(bhist, 0, NTILE*4, stream);
  prep_gen<<<PREP_BLOCKS + GEN_BLOCKS, 256, 0, stream>>>(kr, ki, dc, ktraj, ydc, wtab,
                                                         itab, bhist, B1, W2c, W2s);
  bin_scan<<<1, 256, 0, stream>>>(bhist, bstart, bcur);
  bin_fill<<<(MPTS+255)/256, 256, 0, stream>>>(itab, bcur, bent);
  if (bc < NC) hipMemsetAsync(accum, 0, acc_b, stream);

  // ---- per coil-batch pipeline ----
  for (int c0 = 0; c0 < NC; c0 += bc){
    int nb = NC - c0; if (nb > bc) nb = bc;
    int ncols = nb*2560;

    launch_gather(nb, ydc, wtab, itab, bstart, bcur, bent, A1, c0, stream);

    // GEMM1 with in-staging ky-fold + 2-deep register prefetch
    gemm1_fold<<<3*(ncols/BN), 512, 0, stream>>>(B1, A1, C1t, ncols);

    int tot2 = nb*161*80;
    pack_fold<<<(tot2+255)/256, 256, 0, stream>>>(C1t, A2p, A2m, nb, ncols);

    // GEMM2 (folded): 64x128 tiles; z=0 Oc = W2c x A2p^T, z=1 Os = W2s x A2m^T
    gemm2_wide<<<dim3(M2F/64, nb*640/128, 2), 256, 0, stream>>>(W2c, A2p, Oc,
                                                                W2s, A2m, Os,
                                                                K2F, nb*640);

    if (bc >= NC){
      combine_final<<<(CROPN*CROPN+255)/256, 256, 0, stream>>>(Oc, Os, smr, smi, out, nb, nb*640);
    } else {
      combine<<<(CROPN*CROPN+255)/256, 256, 0, stream>>>(Oc, Os, smr, smi, accum, c0, nb, nb*640);
    }
  }
  if (bc < NC)
    final_mag<<<(CROPN*CROPN+255)/256, 256, 0, stream>>>(accum, out);
}